// Round 3
// baseline (794.799 us; speedup 1.0000x reference)
//
#include <hip/hip_runtime.h>
#include <hip/hip_bf16.h>
#include <math.h>

typedef __attribute__((ext_vector_type(8))) __bf16 bf16x8;
typedef __attribute__((ext_vector_type(4))) float f32x4;

#define HH 256
#define WW 256
#define SCALEF 0.08838834764831845f  // 128^-0.5

// ---------------------------------------------------------------------------
// K1: NCHW f32 -> NHWC bf16 transpose
// ---------------------------------------------------------------------------
__global__ __launch_bounds__(256) void transpose_nhwc(const float* __restrict__ in,
                                                      __hip_bfloat16* __restrict__ out)
{
    int blk = blockIdx.x;
    int c0 = (blk & 3) * 32;
    int x0 = ((blk >> 2) & 7) * 32;
    int by = blk >> 5;              // b*256 + y
    int y = by & 255, b = by >> 8;
    __shared__ float tile[32][33];
    int tx = threadIdx.x & 31, ty = threadIdx.x >> 5;   // ty 0..7
#pragma unroll
    for (int i = 0; i < 4; i++) {
        int c = c0 + ty + 8 * i;
        tile[ty + 8 * i][tx] = in[(((size_t)b * 128 + c) * HH + y) * WW + x0 + tx];
    }
    __syncthreads();
#pragma unroll
    for (int i = 0; i < 4; i++) {
        int x = x0 + ty + 8 * i;
        out[(((size_t)b * HH + y) * WW + x) * 128 + c0 + tx] =
            __float2bfloat16(tile[tx][ty + 8 * i]);
    }
}

// ---------------------------------------------------------------------------
// K2: weight repack (co,ci,ky,kx) f32 -> W2[co][ (ky*3+kx)*128 + ci ] bf16
// ---------------------------------------------------------------------------
__global__ __launch_bounds__(256) void prep_w(const float* __restrict__ wq,
                                              const float* __restrict__ wk,
                                              __hip_bfloat16* __restrict__ w2q,
                                              __hip_bfloat16* __restrict__ w2k)
{
    int i = blockIdx.x * 256 + threadIdx.x;
    if (i >= 128 * 128 * 9) return;
    int co = i / (128 * 9);
    int r = i - co * 128 * 9;
    int ci = r / 9;
    int t = r - ci * 9;
    int dst = co * 1152 + t * 128 + ci;
    w2q[dst] = __float2bfloat16(wq[i]);
    w2k[dst] = __float2bfloat16(wk[i]);
}

// ---------------------------------------------------------------------------
// K3: conv3x3 (SAME) as implicit GEMM with MFMA bf16.
// Block: 16x8 pixel tile (M=128), all 128 co. 4 waves, wave w: co [32w,32w+32).
// Epilogue stages output in LDS (aliased over patch) -> coalesced uint4 stores.
// ---------------------------------------------------------------------------
#define PPAD 136      // patch row stride (el): 272B, 17 chunks -> good spread
#define OST 132       // out-stage row stride (el): 264B -> conflict-free acc writes
__global__ __launch_bounds__(256, 2) void conv3x3_mfma(
    const __hip_bfloat16* __restrict__ in0, const __hip_bfloat16* __restrict__ in1,
    const __hip_bfloat16* __restrict__ w2q, const __hip_bfloat16* __restrict__ w2k,
    const float* __restrict__ bq, const float* __restrict__ bk,
    __hip_bfloat16* __restrict__ q0, __hip_bfloat16* __restrict__ k0,
    __hip_bfloat16* __restrict__ q2, __hip_bfloat16* __restrict__ k2)
{
    const int cid = blockIdx.y;
    const __hip_bfloat16* src = (cid >= 2) ? in1 : in0;
    const __hip_bfloat16* wmat = (cid & 1) ? w2k : w2q;
    const float* bias = (cid & 1) ? bk : bq;
    __hip_bfloat16* dst = (cid == 0) ? q0 : (cid == 1) ? k0 : (cid == 2) ? q2 : k2;

    const int blk = blockIdx.x;            // 0..1023
    const int b = blk >> 9;
    const int rr = blk & 511;
    const int y0 = (rr >> 4) << 3;         // 8-row tiles
    const int x0 = (rr & 15) << 4;         // 16-col tiles

    __shared__ __align__(16) char smem[180 * PPAD * 2];   // 48960 B
    __hip_bfloat16* patch = (__hip_bfloat16*)smem;        // [10][18] x 128ch, stride PPAD
    __hip_bfloat16* stage = (__hip_bfloat16*)smem;        // [128 px][128 ch], stride OST

    const int tid = threadIdx.x;
    for (int idx = tid; idx < 2880; idx += 256) {          // 180 pos x 16 uint4
        int p = idx >> 4, lc = idx & 15;
        int py = p / 18, px = p - py * 18;
        int gy = y0 + py - 1, gx = x0 + px - 1;
        uint4 v = make_uint4(0u, 0u, 0u, 0u);
        if (gy >= 0 && gy < HH && gx >= 0 && gx < WW)
            v = *(const uint4*)(src + ((((size_t)b * HH + gy) * WW + gx) << 7) + lc * 8);
        *(uint4*)(patch + p * PPAD + lc * 8) = v;
    }
    __syncthreads();

    const int lane = tid & 63;
    const int wv = tid >> 6;
    const int l15 = lane & 15;
    const int kq = lane >> 4;

    f32x4 acc[8][2];
#pragma unroll
    for (int mi = 0; mi < 8; mi++)
#pragma unroll
        for (int n = 0; n < 2; n++) acc[mi][n] = (f32x4){0.f, 0.f, 0.f, 0.f};

    const __hip_bfloat16* wcol0 = wmat + (size_t)(wv * 32 + l15) * 1152;
    const __hip_bfloat16* wcol1 = wmat + (size_t)(wv * 32 + 16 + l15) * 1152;

#pragma unroll
    for (int t = 0; t < 9; ++t) {
        int ky = t / 3, kx = t - ky * 3;
#pragma unroll
        for (int cc = 0; cc < 4; ++cc) {
            int k = t * 128 + cc * 32 + kq * 8;
            bf16x8 b0 = *(const bf16x8*)(wcol0 + k);
            bf16x8 b1 = *(const bf16x8*)(wcol1 + k);
#pragma unroll
            for (int mi = 0; mi < 8; ++mi) {
                // pixel p = mi*16 + l15 -> row mi, col l15 of the 8x16 tile
                bf16x8 a = *(const bf16x8*)(patch + ((mi + ky) * 18 + (l15 + kx)) * PPAD + cc * 32 + kq * 8);
                acc[mi][0] = __builtin_amdgcn_mfma_f32_16x16x32_bf16(a, b0, acc[mi][0], 0, 0, 0);
                acc[mi][1] = __builtin_amdgcn_mfma_f32_16x16x32_bf16(a, b1, acc[mi][1], 0, 0, 0);
            }
        }
    }
    __syncthreads();   // all patch reads done before stage overwrite

    float bv0 = bias[wv * 32 + l15];
    float bv1 = bias[wv * 32 + 16 + l15];
#pragma unroll
    for (int mi = 0; mi < 8; ++mi) {
#pragma unroll
        for (int r = 0; r < 4; ++r) {
            int p = mi * 16 + kq * 4 + r;
            stage[p * OST + wv * 32 + l15] = __float2bfloat16(acc[mi][0][r] + bv0);
            stage[p * OST + wv * 32 + 16 + l15] = __float2bfloat16(acc[mi][1][r] + bv1);
        }
    }
    __syncthreads();

#pragma unroll
    for (int it = 0; it < 8; ++it) {
        int idx = it * 256 + tid;
        int p = idx >> 4, lc = idx & 15;
        int y = y0 + (p >> 4), x = x0 + (p & 15);
        uint4 v = *(const uint4*)(stage + p * OST + lc * 8);
        *(uint4*)(dst + ((((size_t)b * HH + y) * WW + x) << 7) + lc * 8) = v;
    }
}

// ---------------------------------------------------------------------------
// K4: per-(window, estimate x shift) correlation + flow_bsd + flow_mid
// writes spliced+rolled flow fields directly.
// Softmax phases are wave-parallel: 16-lane groups per row, shfl_xor reduce.
// ---------------------------------------------------------------------------
#define WPAD 136     // 272B rows: 16B-aligned, stride 4 dwords mod 32 -> 2-way (free)
#define CST 66       // cls row stride (floats)
__global__ __launch_bounds__(256, 3) void window_flow(
    const __hip_bfloat16* __restrict__ q0, const __hip_bfloat16* __restrict__ k0,
    const __hip_bfloat16* __restrict__ q2, const __hip_bfloat16* __restrict__ k2,
    const float* __restrict__ btab,
    float* __restrict__ f1e0, float* __restrict__ f1e1,
    float* __restrict__ f0e0, float* __restrict__ f0e1)
{
    const int combo = blockIdx.y;            // 0..7
    const int e = combo >> 2;
    const int sflag = combo & 3;
    const int shq = (sflag >> 1) & 1;        // shift_h flag == quadrant y
    const int swq = sflag & 1;               // shift_w flag == quadrant x
    const int sh = shq ? 4 : 0, sw = swq ? 4 : 0;
    const __hip_bfloat16* qf = e ? q2 : q0;
    const __hip_bfloat16* kf = e ? k0 : k2;
    float* f1 = e ? f1e1 : f1e0;
    float* f0 = e ? f0e1 : f0e0;

    const int wdx = blockIdx.x;              // 0..2047
    const int b = wdx >> 10;
    const int s1i = (wdx >> 5) & 31;
    const int s2i = wdx & 31;

    __shared__ __align__(16) __hip_bfloat16 qt[64 * WPAD];
    __shared__ __align__(16) __hip_bfloat16 kt[64 * WPAD];
    __shared__ float cls[64 * CST];
    __shared__ float cmid[81], fxm[81], fym[81];
    __shared__ float sb[225];

    const int tid = threadIdx.x;
    if (tid < 225) sb[tid] = btab[tid];

    for (int idx = tid; idx < 2048; idx += 256) {
        int which = idx >> 10;
        int p = (idx >> 4) & 63, lc = idx & 15;
        int iy = p >> 3, ix = p & 7;
        int gy = (s1i * 8 + iy + sh) & 255;
        int gx = (s2i * 8 + ix + sw) & 255;
        const __hip_bfloat16* srcf = which ? kf : qf;
        uint4 v = *(const uint4*)(srcf + ((((size_t)b * HH + gy) * WW + gx) << 7) + lc * 8);
        __hip_bfloat16* dstt = which ? kt : qt;
        *(uint4*)(dstt + p * WPAD + lc * 8) = v;
    }
    __syncthreads();

    // corr = qw . kw^T   (M=64, N=64, K=128), 4 waves over M
    const int lane = tid & 63;
    const int wv = tid >> 6;
    const int l15 = lane & 15;
    const int kq = lane >> 4;

    f32x4 acc[4];
#pragma unroll
    for (int nf = 0; nf < 4; nf++) acc[nf] = (f32x4){0.f, 0.f, 0.f, 0.f};

#pragma unroll
    for (int kc = 0; kc < 4; ++kc) {
        bf16x8 a = *(const bf16x8*)(qt + (wv * 16 + l15) * WPAD + kc * 32 + kq * 8);
#pragma unroll
        for (int nf = 0; nf < 4; ++nf) {
            bf16x8 bb = *(const bf16x8*)(kt + (nf * 16 + l15) * WPAD + kc * 32 + kq * 8);
            acc[nf] = __builtin_amdgcn_mfma_f32_16x16x32_bf16(a, bb, acc[nf], 0, 0, 0);
        }
    }

    // epilogue: scale + relative-pos bias + shift mask -> cls
#pragma unroll
    for (int nf = 0; nf < 4; ++nf) {
#pragma unroll
        for (int r = 0; r < 4; ++r) {
            int row = wv * 16 + kq * 4 + r;
            int col = nf * 16 + l15;
            int qy = row >> 3, qx = row & 7;
            int ty = col >> 3, tx = col & 7;
            float v = acc[nf][r] * SCALEF + sb[(qy - ty + 7) * 15 + (qx - tx + 7)];
            if (sflag) {
                int rhq = 0, rwq = 0, rht = 0, rwt = 0;
                if (shq && s1i == 31) { rhq = (qy < 4) ? 1 : 2; rht = (ty < 4) ? 1 : 2; }
                if (swq && s2i == 31) { rwq = (qx < 4) ? 1 : 2; rwt = (tx < 4) ? 1 : 2; }
                int regq, regt;
                if (shq && swq) { regq = rhq * 3 + rwq; regt = rht * 3 + rwt; }
                else if (shq)   { regq = rhq; regt = rht; }
                else            { regq = rwq; regt = rwt; }
                if (regq != regt) v -= 10000.0f;
            }
            cls[row * CST + col] = v;
        }
    }
    __syncthreads();

    const int rg = tid >> 4;       // 16 row-groups
    const int lg = tid & 15;       // 16 lanes per row

    // ---- flow_bsd: 16 rows, one 16-lane group each, 4 cols/lane ----
    {
        int fy = rg >> 2, fx = rg & 3;
        int qy = fy + 2, qx = fx + 2;
        const float* rowp = &cls[(qy * 8 + qx) * CST];
        float v[4];
        float mx = -1e30f;
#pragma unroll
        for (int j = 0; j < 4; ++j) { v[j] = rowp[lg + 16 * j]; mx = fmaxf(mx, v[j]); }
#pragma unroll
        for (int m = 8; m >= 1; m >>= 1) mx = fmaxf(mx, __shfl_xor(mx, m));
        float S = 0.f, sx = 0.f, sy = 0.f;
#pragma unroll
        for (int j = 0; j < 4; ++j) {
            int t = lg + 16 * j;
            float p = __expf(v[j] - mx);
            S += p; sx += p * (float)(t & 7); sy += p * (float)(t >> 3);
        }
#pragma unroll
        for (int m = 8; m >= 1; m >>= 1) {
            S += __shfl_xor(S, m); sx += __shfl_xor(sx, m); sy += __shfl_xor(sy, m);
        }
        if (lg == 0) {
            float fxv = sx / S - (float)qx;
            float fyv = sy / S - (float)qy;
            int Y = (s1i * 8 + shq * 4 + fy + 2) & 255;
            int X = (s2i * 8 + swq * 4 + fx + 2) & 255;
            size_t base = (size_t)b * 2 * HH * WW;
            f0[base + (size_t)Y * WW + X] = fxv;
            f0[base + (size_t)HH * WW + (size_t)Y * WW + X] = fyv;
        }
    }

    // ---- flow_mid row softmaxes: 81 rows, 16 at a time ----
    for (int it = 0; it < 6; ++it) {
        int rm = it * 16 + rg;
        if (rm < 81) {
            int a = rm / 9, bc = rm - a * 9;
            float v[4];
            float mx = -1e30f;
#pragma unroll
            for (int j = 0; j < 4; ++j) {
                int t = lg + 16 * j;
                int h2 = t >> 3, w2 = t & 7;
                int qy = a + 3 - h2, qx = bc + 3 - w2;
                v[j] = (qy >= 0 && qy < 8 && qx >= 0 && qx < 8) ? cls[(qy * 8 + qx) * CST + t] : 0.0f;
                mx = fmaxf(mx, v[j]);
            }
#pragma unroll
            for (int m = 8; m >= 1; m >>= 1) mx = fmaxf(mx, __shfl_xor(mx, m));
            float S = 0.f, sc = 0.f, sx = 0.f, sy = 0.f;
#pragma unroll
            for (int j = 0; j < 4; ++j) {
                int t = lg + 16 * j;
                float p = __expf(v[j] - mx);
                S += p; sc += v[j] * p; sx += p * (float)(t & 7); sy += p * (float)(t >> 3);
            }
#pragma unroll
            for (int m = 8; m >= 1; m >>= 1) {
                S += __shfl_xor(S, m); sc += __shfl_xor(sc, m);
                sx += __shfl_xor(sx, m); sy += __shfl_xor(sy, m);
            }
            if (lg == 0) {
                float inv = 1.0f / S;
                cmid[rm] = sc * inv;
                fxm[rm] = sx * inv - (float)(bc + 3) * 0.5f;
                fym[rm] = sy * inv - (float)(a + 3) * 0.5f;
            }
        }
    }
    __syncthreads();

    // flow_mid quadrant combine -> 8x8
    if (tid < 64) {
        int fy = tid >> 3, fx = tid & 7;
        int i00 = fy * 9 + fx, i01 = i00 + 1, i10 = i00 + 9, i11 = i00 + 10;
        float c00 = cmid[i00], c01 = cmid[i01], c10 = cmid[i10], c11 = cmid[i11];
        float m = fmaxf(fmaxf(c00, c01), fmaxf(c10, c11));
        float p0 = __expf(c00 - m), p1 = __expf(c01 - m), p2 = __expf(c10 - m), p3 = __expf(c11 - m);
        float S = p0 + p1 + p2 + p3;
        float ox = 2.0f * (p0 * fxm[i00] + p1 * fxm[i01] + p2 * fxm[i10] + p3 * fxm[i11]) / S;
        float oy = 2.0f * (p0 * fym[i00] + p1 * fym[i01] + p2 * fym[i10] + p3 * fym[i11]) / S;
        int Y = (s1i * 16 + shq * 8 + fy + 4) & 511;
        int X = (s2i * 16 + swq * 8 + fx + 4) & 511;
        size_t base = (size_t)b * 2 * 512 * 512;
        f1[base + (size_t)Y * 512 + X] = ox;
        f1[base + (size_t)512 * 512 + (size_t)Y * 512 + X] = oy;
    }
}

// ---------------------------------------------------------------------------
// K5: bilinear resize (half-pixel, edge clamp) + scale, concat 4 outputs
// ---------------------------------------------------------------------------
__global__ __launch_bounds__(256) void resize_out(
    const float* __restrict__ f1e0, const float* __restrict__ f1e1,
    const float* __restrict__ f0e0, const float* __restrict__ f0e1,
    float* __restrict__ out)
{
    int idx = blockIdx.x * 256 + threadIdx.x;       // 0 .. 16777215
    int o = idx >> 22;
    int rem = idx & 4194303;
    int bc = rem >> 20;                              // b*2+ch
    int Y = (rem >> 10) & 1023;
    int X = rem & 1023;
    const float* src; int n; float invf, sc;
    if (o == 0)      { src = f1e1; n = 512; invf = 0.5f;  sc = 2.f; }
    else if (o == 1) { src = f1e0; n = 512; invf = 0.5f;  sc = 2.f; }
    else if (o == 2) { src = f0e0; n = 256; invf = 0.25f; sc = 4.f; }
    else             { src = f0e1; n = 256; invf = 0.25f; sc = 4.f; }
    float syf = ((float)Y + 0.5f) * invf - 0.5f;
    float sxf = ((float)X + 0.5f) * invf - 0.5f;
    int iy = (int)floorf(syf), ix = (int)floorf(sxf);
    float wy = syf - (float)iy, wx = sxf - (float)ix;
    int y0c = min(max(iy, 0), n - 1), y1c = min(max(iy + 1, 0), n - 1);
    int x0c = min(max(ix, 0), n - 1), x1c = min(max(ix + 1, 0), n - 1);
    const float* s = src + (size_t)bc * n * n;
    float v00 = s[(size_t)y0c * n + x0c], v01 = s[(size_t)y0c * n + x1c];
    float v10 = s[(size_t)y1c * n + x0c], v11 = s[(size_t)y1c * n + x1c];
    float v = (1.f - wy) * ((1.f - wx) * v00 + wx * v01) + wy * ((1.f - wx) * v10 + wx * v11);
    out[idx] = v * sc;
}

// ---------------------------------------------------------------------------
extern "C" void kernel_launch(void* const* d_in, const int* in_sizes, int n_in,
                              void* d_out, int out_size, void* d_ws, size_t ws_size,
                              hipStream_t stream)
{
    const float* feat0 = (const float*)d_in[0];
    const float* feat2 = (const float*)d_in[1];
    const float* wq = (const float*)d_in[2];
    const float* bq = (const float*)d_in[3];
    const float* wk = (const float*)d_in[4];
    const float* bk = (const float*)d_in[5];
    const float* btab = (const float*)d_in[6];

    char* w = (char*)d_ws;
    const size_t F = (size_t)16777216 * 2;   // bytes per bf16 NHWC field (2*256*256*128)
    __hip_bfloat16* q0 = (__hip_bfloat16*)(w);
    __hip_bfloat16* k0 = (__hip_bfloat16*)(w + F);
    __hip_bfloat16* q2 = (__hip_bfloat16*)(w + 2 * F);
    __hip_bfloat16* k2 = (__hip_bfloat16*)(w + 3 * F);
    __hip_bfloat16* in0T = (__hip_bfloat16*)(w + 4 * F);
    __hip_bfloat16* in1T = (__hip_bfloat16*)(w + 5 * F);
    __hip_bfloat16* w2q = (__hip_bfloat16*)(w + 6 * F);
    __hip_bfloat16* w2k = (__hip_bfloat16*)(w + 6 * F + 294912);
    float* f1e0 = (float*)(w + 6 * F + 2 * 294912);
    float* f1e1 = f1e0 + 1048576;   // 2*2*512*512
    float* f0e0 = f1e1 + 1048576;
    float* f0e1 = f0e0 + 262144;    // 2*2*256*256

    hipLaunchKernelGGL(transpose_nhwc, dim3(16384), dim3(256), 0, stream, feat0, in0T);
    hipLaunchKernelGGL(transpose_nhwc, dim3(16384), dim3(256), 0, stream, feat2, in1T);
    hipLaunchKernelGGL(prep_w, dim3(576), dim3(256), 0, stream, wq, wk, w2q, w2k);
    hipLaunchKernelGGL(conv3x3_mfma, dim3(1024, 4), dim3(256), 0, stream,
                       in0T, in1T, w2q, w2k, bq, bk, q0, k0, q2, k2);
    hipLaunchKernelGGL(window_flow, dim3(2048, 8), dim3(256), 0, stream,
                       q0, k0, q2, k2, btab, f1e0, f1e1, f0e0, f0e1);
    hipLaunchKernelGGL(resize_out, dim3(65536), dim3(256), 0, stream,
                       f1e0, f1e1, f0e0, f0e1, (float*)d_out);
}

// Round 4
// 463.813 us; speedup vs baseline: 1.7136x; 1.7136x over previous
//
#include <hip/hip_runtime.h>
#include <hip/hip_bf16.h>
#include <math.h>

typedef __attribute__((ext_vector_type(8))) __bf16 bf16x8;
typedef __attribute__((ext_vector_type(4))) float f32x4;

#define HH 256
#define WW 256
#define SCALEF 0.08838834764831845f  // 128^-0.5

__device__ __forceinline__ void gload_lds16(const void* g, void* l) {
    __builtin_amdgcn_global_load_lds(
        (const __attribute__((address_space(1))) void*)g,
        (__attribute__((address_space(3))) void*)l, 16, 0, 0);
}

// ---------------------------------------------------------------------------
// K1: NCHW f32 -> NHWC bf16 transpose
// ---------------------------------------------------------------------------
__global__ __launch_bounds__(256) void transpose_nhwc(const float* __restrict__ in,
                                                      __hip_bfloat16* __restrict__ out)
{
    int blk = blockIdx.x;
    int c0 = (blk & 3) * 32;
    int x0 = ((blk >> 2) & 7) * 32;
    int by = blk >> 5;              // b*256 + y
    int y = by & 255, b = by >> 8;
    __shared__ float tile[32][33];
    int tx = threadIdx.x & 31, ty = threadIdx.x >> 5;   // ty 0..7
#pragma unroll
    for (int i = 0; i < 4; i++) {
        int c = c0 + ty + 8 * i;
        tile[ty + 8 * i][tx] = in[(((size_t)b * 128 + c) * HH + y) * WW + x0 + tx];
    }
    __syncthreads();
#pragma unroll
    for (int i = 0; i < 4; i++) {
        int x = x0 + ty + 8 * i;
        out[(((size_t)b * HH + y) * WW + x) * 128 + c0 + tx] =
            __float2bfloat16(tile[tx][ty + 8 * i]);
    }
}

// ---------------------------------------------------------------------------
// K2: weight repack -> chunk-major, swizzled for global_load_lds staging.
// src (co,ci,ky,kx). k_global = tap*128+ci. chunk q = k_global>>5 (32-k chunks).
// dst elem = q*4096 + co*32 + ((kin>>3) ^ ((co>>1)&3))*8 + (kin&7), kin=k_global&31
// ---------------------------------------------------------------------------
__global__ __launch_bounds__(256) void prep_w(const float* __restrict__ wq,
                                              const float* __restrict__ wk,
                                              __hip_bfloat16* __restrict__ w3q,
                                              __hip_bfloat16* __restrict__ w3k)
{
    int i = blockIdx.x * 256 + threadIdx.x;
    if (i >= 128 * 128 * 9) return;
    int co = i / (128 * 9);
    int r = i - co * 128 * 9;
    int ci = r / 9;
    int tap = r - ci * 9;
    int kg = tap * 128 + ci;
    int q = kg >> 5, kin = kg & 31;
    int slot = (kin >> 3) ^ ((co >> 1) & 3);
    int dst = q * 4096 + co * 32 + slot * 8 + (kin & 7);
    w3q[dst] = __float2bfloat16(wq[i]);
    w3k[dst] = __float2bfloat16(wk[i]);
}

// ---------------------------------------------------------------------------
// K3: conv3x3 (SAME) implicit GEMM. M=64 (8x8 px), 128 co, 4 waves (32 co each).
// A: halo patch in LDS (swizzled, unpadded 256B rows).
// B: 32-k chunks double-buffered in LDS via async global_load_lds (16B).
// Out: staged in LDS (aliases patch) -> coalesced uint4 stores.
// ---------------------------------------------------------------------------
__global__ __launch_bounds__(256, 3) void conv3x3_mfma(
    const __hip_bfloat16* __restrict__ in0, const __hip_bfloat16* __restrict__ in1,
    const __hip_bfloat16* __restrict__ w3q, const __hip_bfloat16* __restrict__ w3k,
    const float* __restrict__ bq, const float* __restrict__ bk,
    __hip_bfloat16* __restrict__ q0, __hip_bfloat16* __restrict__ k0,
    __hip_bfloat16* __restrict__ q2, __hip_bfloat16* __restrict__ k2)
{
    const int cid = blockIdx.y;
    const __hip_bfloat16* src = (cid >= 2) ? in1 : in0;
    const __hip_bfloat16* wmat = (cid & 1) ? w3k : w3q;
    const float* bias = (cid & 1) ? bk : bq;
    __hip_bfloat16* dst = (cid == 0) ? q0 : (cid == 1) ? k0 : (cid == 2) ? q2 : k2;

    const int blk = blockIdx.x;           // 0..2047
    const int b = blk >> 10;
    const int rr = blk & 1023;
    const int y0 = (rr >> 5) << 3;
    const int x0 = (rr & 31) << 3;

    __shared__ __align__(16) char smem[25600 + 16384];   // patch 100*256B + B dbuf 2*8KB
    char* patch = smem;
    char* ldsB = smem + 25600;

    const int tid = threadIdx.x;

    // ---- stage input halo patch (swizzled 16B slots) ----
    for (int idx = tid; idx < 1600; idx += 256) {
        int p = idx >> 4, lc = idx & 15;
        int py = p / 10, px = p - py * 10;
        int gy = y0 + py - 1, gx = x0 + px - 1;
        uint4 v = make_uint4(0u, 0u, 0u, 0u);
        if (gy >= 0 && gy < HH && gx >= 0 && gx < WW)
            v = *(const uint4*)(src + ((((size_t)b * HH + gy) * WW + gx) << 7) + lc * 8);
        *(uint4*)(patch + p * 256 + ((lc ^ (p & 7)) << 4)) = v;
    }
    // ---- async-stage B chunk 0 into buf 0 ----
    {
        const char* s = (const char*)wmat + tid * 16;
        char* dl = ldsB + tid * 16;
        gload_lds16(s, dl);
        gload_lds16(s + 4096, dl + 4096);
    }
    __syncthreads();

    const int lane = tid & 63;
    const int wv = tid >> 6;
    const int l15 = lane & 15;
    const int kq = lane >> 4;
    const int myb = l15 >> 3, mxb = l15 & 7;
    const int c0 = wv * 32 + l15;
    const int c1 = c0 + 16;
    const int bswz = ((kq ^ ((l15 >> 1) & 3)) << 4);
    const int bO0 = c0 * 64 + bswz;
    const int bO1 = c1 * 64 + bswz;

    f32x4 acc[4][2];
#pragma unroll
    for (int mi = 0; mi < 4; mi++)
#pragma unroll
        for (int n = 0; n < 2; n++) acc[mi][n] = (f32x4){0.f, 0.f, 0.f, 0.f};

#pragma unroll
    for (int t = 0; t < 9; ++t) {
        const int ky = t / 3, kx = t - ky * 3;
#pragma unroll
        for (int cc = 0; cc < 4; ++cc) {
            const int q = t * 4 + cc;
            if (q + 1 < 36) {                 // async prefetch next chunk
                const char* s = (const char*)wmat + (size_t)(q + 1) * 8192 + tid * 16;
                char* dl = ldsB + ((q + 1) & 1) * 8192 + tid * 16;
                gload_lds16(s, dl);
                gload_lds16(s + 4096, dl + 4096);
            }
            const char* bb = ldsB + (q & 1) * 8192;
            bf16x8 b0 = *(const bf16x8*)(bb + bO0);
            bf16x8 b1 = *(const bf16x8*)(bb + bO1);
            const int slot = cc * 4 + kq;
#pragma unroll
            for (int mi = 0; mi < 4; ++mi) {
                int pos = (mi * 2 + myb + ky) * 10 + (mxb + kx);
                bf16x8 a = *(const bf16x8*)(patch + pos * 256 + ((slot ^ (pos & 7)) << 4));
                acc[mi][0] = __builtin_amdgcn_mfma_f32_16x16x32_bf16(a, b0, acc[mi][0], 0, 0, 0);
                acc[mi][1] = __builtin_amdgcn_mfma_f32_16x16x32_bf16(a, b1, acc[mi][1], 0, 0, 0);
            }
            __syncthreads();
        }
    }

    // ---- epilogue: bias, stage in LDS (aliases patch), coalesced store ----
    float bv0 = bias[c0];
    float bv1 = bias[c1];
    __hip_bfloat16* stage = (__hip_bfloat16*)patch;   // [64 px][stride 136 el]
#pragma unroll
    for (int mi = 0; mi < 4; ++mi) {
#pragma unroll
        for (int r = 0; r < 4; ++r) {
            int m = mi * 16 + kq * 4 + r;
            stage[m * 136 + c0] = __float2bfloat16(acc[mi][0][r] + bv0);
            stage[m * 136 + c1] = __float2bfloat16(acc[mi][1][r] + bv1);
        }
    }
    __syncthreads();

#pragma unroll
    for (int it = 0; it < 4; ++it) {
        int idx = it * 256 + tid;
        int p = idx >> 4, lc = idx & 15;
        int y = y0 + (p >> 3), x = x0 + (p & 7);
        uint4 v = *(const uint4*)((const char*)patch + p * 272 + lc * 16);
        *(uint4*)(dst + ((((size_t)b * HH + y) * WW + x) << 7) + lc * 8) = v;
    }
}

// ---------------------------------------------------------------------------
// K4: per-(window, estimate x shift) correlation + flow_bsd + flow_mid
// writes spliced+rolled flow fields directly.
// Softmax phases are wave-parallel: 16-lane groups per row, shfl_xor reduce.
// ---------------------------------------------------------------------------
#define WPAD 136     // 272B rows: 16B-aligned, stride 4 dwords mod 32 -> 2-way (free)
#define CST 66       // cls row stride (floats)
__global__ __launch_bounds__(256, 3) void window_flow(
    const __hip_bfloat16* __restrict__ q0, const __hip_bfloat16* __restrict__ k0,
    const __hip_bfloat16* __restrict__ q2, const __hip_bfloat16* __restrict__ k2,
    const float* __restrict__ btab,
    float* __restrict__ f1e0, float* __restrict__ f1e1,
    float* __restrict__ f0e0, float* __restrict__ f0e1)
{
    const int combo = blockIdx.y;            // 0..7
    const int e = combo >> 2;
    const int sflag = combo & 3;
    const int shq = (sflag >> 1) & 1;        // shift_h flag == quadrant y
    const int swq = sflag & 1;               // shift_w flag == quadrant x
    const int sh = shq ? 4 : 0, sw = swq ? 4 : 0;
    const __hip_bfloat16* qf = e ? q2 : q0;
    const __hip_bfloat16* kf = e ? k0 : k2;
    float* f1 = e ? f1e1 : f1e0;
    float* f0 = e ? f0e1 : f0e0;

    const int wdx = blockIdx.x;              // 0..2047
    const int b = wdx >> 10;
    const int s1i = (wdx >> 5) & 31;
    const int s2i = wdx & 31;

    __shared__ __align__(16) __hip_bfloat16 qt[64 * WPAD];
    __shared__ __align__(16) __hip_bfloat16 kt[64 * WPAD];
    __shared__ float cls[64 * CST];
    __shared__ float cmid[81], fxm[81], fym[81];
    __shared__ float sb[225];

    const int tid = threadIdx.x;
    if (tid < 225) sb[tid] = btab[tid];

    for (int idx = tid; idx < 2048; idx += 256) {
        int which = idx >> 10;
        int p = (idx >> 4) & 63, lc = idx & 15;
        int iy = p >> 3, ix = p & 7;
        int gy = (s1i * 8 + iy + sh) & 255;
        int gx = (s2i * 8 + ix + sw) & 255;
        const __hip_bfloat16* srcf = which ? kf : qf;
        uint4 v = *(const uint4*)(srcf + ((((size_t)b * HH + gy) * WW + gx) << 7) + lc * 8);
        __hip_bfloat16* dstt = which ? kt : qt;
        *(uint4*)(dstt + p * WPAD + lc * 8) = v;
    }
    __syncthreads();

    // corr = qw . kw^T   (M=64, N=64, K=128), 4 waves over M
    const int lane = tid & 63;
    const int wv = tid >> 6;
    const int l15 = lane & 15;
    const int kq = lane >> 4;

    f32x4 acc[4];
#pragma unroll
    for (int nf = 0; nf < 4; nf++) acc[nf] = (f32x4){0.f, 0.f, 0.f, 0.f};

#pragma unroll
    for (int kc = 0; kc < 4; ++kc) {
        bf16x8 a = *(const bf16x8*)(qt + (wv * 16 + l15) * WPAD + kc * 32 + kq * 8);
#pragma unroll
        for (int nf = 0; nf < 4; ++nf) {
            bf16x8 bb = *(const bf16x8*)(kt + (nf * 16 + l15) * WPAD + kc * 32 + kq * 8);
            acc[nf] = __builtin_amdgcn_mfma_f32_16x16x32_bf16(a, bb, acc[nf], 0, 0, 0);
        }
    }

    // epilogue: scale + relative-pos bias + shift mask -> cls
#pragma unroll
    for (int nf = 0; nf < 4; ++nf) {
#pragma unroll
        for (int r = 0; r < 4; ++r) {
            int row = wv * 16 + kq * 4 + r;
            int col = nf * 16 + l15;
            int qy = row >> 3, qx = row & 7;
            int ty = col >> 3, tx = col & 7;
            float v = acc[nf][r] * SCALEF + sb[(qy - ty + 7) * 15 + (qx - tx + 7)];
            if (sflag) {
                int rhq = 0, rwq = 0, rht = 0, rwt = 0;
                if (shq && s1i == 31) { rhq = (qy < 4) ? 1 : 2; rht = (ty < 4) ? 1 : 2; }
                if (swq && s2i == 31) { rwq = (qx < 4) ? 1 : 2; rwt = (tx < 4) ? 1 : 2; }
                int regq, regt;
                if (shq && swq) { regq = rhq * 3 + rwq; regt = rht * 3 + rwt; }
                else if (shq)   { regq = rhq; regt = rht; }
                else            { regq = rwq; regt = rwt; }
                if (regq != regt) v -= 10000.0f;
            }
            cls[row * CST + col] = v;
        }
    }
    __syncthreads();

    const int rg = tid >> 4;       // 16 row-groups
    const int lg = tid & 15;       // 16 lanes per row

    // ---- flow_bsd: 16 rows, one 16-lane group each, 4 cols/lane ----
    {
        int fy = rg >> 2, fx = rg & 3;
        int qy = fy + 2, qx = fx + 2;
        const float* rowp = &cls[(qy * 8 + qx) * CST];
        float v[4];
        float mx = -1e30f;
#pragma unroll
        for (int j = 0; j < 4; ++j) { v[j] = rowp[lg + 16 * j]; mx = fmaxf(mx, v[j]); }
#pragma unroll
        for (int m = 8; m >= 1; m >>= 1) mx = fmaxf(mx, __shfl_xor(mx, m));
        float S = 0.f, sx = 0.f, sy = 0.f;
#pragma unroll
        for (int j = 0; j < 4; ++j) {
            int t = lg + 16 * j;
            float p = __expf(v[j] - mx);
            S += p; sx += p * (float)(t & 7); sy += p * (float)(t >> 3);
        }
#pragma unroll
        for (int m = 8; m >= 1; m >>= 1) {
            S += __shfl_xor(S, m); sx += __shfl_xor(sx, m); sy += __shfl_xor(sy, m);
        }
        if (lg == 0) {
            float fxv = sx / S - (float)qx;
            float fyv = sy / S - (float)qy;
            int Y = (s1i * 8 + shq * 4 + fy + 2) & 255;
            int X = (s2i * 8 + swq * 4 + fx + 2) & 255;
            size_t base = (size_t)b * 2 * HH * WW;
            f0[base + (size_t)Y * WW + X] = fxv;
            f0[base + (size_t)HH * WW + (size_t)Y * WW + X] = fyv;
        }
    }

    // ---- flow_mid row softmaxes: 81 rows, 16 at a time ----
    for (int it = 0; it < 6; ++it) {
        int rm = it * 16 + rg;
        if (rm < 81) {
            int a = rm / 9, bc = rm - a * 9;
            float v[4];
            float mx = -1e30f;
#pragma unroll
            for (int j = 0; j < 4; ++j) {
                int t = lg + 16 * j;
                int h2 = t >> 3, w2 = t & 7;
                int qy = a + 3 - h2, qx = bc + 3 - w2;
                v[j] = (qy >= 0 && qy < 8 && qx >= 0 && qx < 8) ? cls[(qy * 8 + qx) * CST + t] : 0.0f;
                mx = fmaxf(mx, v[j]);
            }
#pragma unroll
            for (int m = 8; m >= 1; m >>= 1) mx = fmaxf(mx, __shfl_xor(mx, m));
            float S = 0.f, sc = 0.f, sx = 0.f, sy = 0.f;
#pragma unroll
            for (int j = 0; j < 4; ++j) {
                int t = lg + 16 * j;
                float p = __expf(v[j] - mx);
                S += p; sc += v[j] * p; sx += p * (float)(t & 7); sy += p * (float)(t >> 3);
            }
#pragma unroll
            for (int m = 8; m >= 1; m >>= 1) {
                S += __shfl_xor(S, m); sc += __shfl_xor(sc, m);
                sx += __shfl_xor(sx, m); sy += __shfl_xor(sy, m);
            }
            if (lg == 0) {
                float inv = 1.0f / S;
                cmid[rm] = sc * inv;
                fxm[rm] = sx * inv - (float)(bc + 3) * 0.5f;
                fym[rm] = sy * inv - (float)(a + 3) * 0.5f;
            }
        }
    }
    __syncthreads();

    // flow_mid quadrant combine -> 8x8
    if (tid < 64) {
        int fy = tid >> 3, fx = tid & 7;
        int i00 = fy * 9 + fx, i01 = i00 + 1, i10 = i00 + 9, i11 = i00 + 10;
        float c00 = cmid[i00], c01 = cmid[i01], c10 = cmid[i10], c11 = cmid[i11];
        float m = fmaxf(fmaxf(c00, c01), fmaxf(c10, c11));
        float p0 = __expf(c00 - m), p1 = __expf(c01 - m), p2 = __expf(c10 - m), p3 = __expf(c11 - m);
        float S = p0 + p1 + p2 + p3;
        float ox = 2.0f * (p0 * fxm[i00] + p1 * fxm[i01] + p2 * fxm[i10] + p3 * fxm[i11]) / S;
        float oy = 2.0f * (p0 * fym[i00] + p1 * fym[i01] + p2 * fym[i10] + p3 * fym[i11]) / S;
        int Y = (s1i * 16 + shq * 8 + fy + 4) & 511;
        int X = (s2i * 16 + swq * 8 + fx + 4) & 511;
        size_t base = (size_t)b * 2 * 512 * 512;
        f1[base + (size_t)Y * 512 + X] = ox;
        f1[base + (size_t)512 * 512 + (size_t)Y * 512 + X] = oy;
    }
}

// ---------------------------------------------------------------------------
// K5: bilinear resize (half-pixel, edge clamp) + scale, concat 4 outputs
// ---------------------------------------------------------------------------
__global__ __launch_bounds__(256) void resize_out(
    const float* __restrict__ f1e0, const float* __restrict__ f1e1,
    const float* __restrict__ f0e0, const float* __restrict__ f0e1,
    float* __restrict__ out)
{
    int idx = blockIdx.x * 256 + threadIdx.x;       // 0 .. 16777215
    int o = idx >> 22;
    int rem = idx & 4194303;
    int bc = rem >> 20;                              // b*2+ch
    int Y = (rem >> 10) & 1023;
    int X = rem & 1023;
    const float* src; int n; float invf, sc;
    if (o == 0)      { src = f1e1; n = 512; invf = 0.5f;  sc = 2.f; }
    else if (o == 1) { src = f1e0; n = 512; invf = 0.5f;  sc = 2.f; }
    else if (o == 2) { src = f0e0; n = 256; invf = 0.25f; sc = 4.f; }
    else             { src = f0e1; n = 256; invf = 0.25f; sc = 4.f; }
    float syf = ((float)Y + 0.5f) * invf - 0.5f;
    float sxf = ((float)X + 0.5f) * invf - 0.5f;
    int iy = (int)floorf(syf), ix = (int)floorf(sxf);
    float wy = syf - (float)iy, wx = sxf - (float)ix;
    int y0c = min(max(iy, 0), n - 1), y1c = min(max(iy + 1, 0), n - 1);
    int x0c = min(max(ix, 0), n - 1), x1c = min(max(ix + 1, 0), n - 1);
    const float* s = src + (size_t)bc * n * n;
    float v00 = s[(size_t)y0c * n + x0c], v01 = s[(size_t)y0c * n + x1c];
    float v10 = s[(size_t)y1c * n + x0c], v11 = s[(size_t)y1c * n + x1c];
    float v = (1.f - wy) * ((1.f - wx) * v00 + wx * v01) + wy * ((1.f - wx) * v10 + wx * v11);
    out[idx] = v * sc;
}

// ---------------------------------------------------------------------------
extern "C" void kernel_launch(void* const* d_in, const int* in_sizes, int n_in,
                              void* d_out, int out_size, void* d_ws, size_t ws_size,
                              hipStream_t stream)
{
    const float* feat0 = (const float*)d_in[0];
    const float* feat2 = (const float*)d_in[1];
    const float* wq = (const float*)d_in[2];
    const float* bq = (const float*)d_in[3];
    const float* wk = (const float*)d_in[4];
    const float* bk = (const float*)d_in[5];
    const float* btab = (const float*)d_in[6];

    char* w = (char*)d_ws;
    const size_t F = (size_t)16777216 * 2;   // bytes per bf16 NHWC field (2*256*256*128)
    __hip_bfloat16* q0 = (__hip_bfloat16*)(w);
    __hip_bfloat16* k0 = (__hip_bfloat16*)(w + F);
    __hip_bfloat16* q2 = (__hip_bfloat16*)(w + 2 * F);
    __hip_bfloat16* k2 = (__hip_bfloat16*)(w + 3 * F);
    __hip_bfloat16* in0T = (__hip_bfloat16*)(w + 4 * F);
    __hip_bfloat16* in1T = (__hip_bfloat16*)(w + 5 * F);
    __hip_bfloat16* w3q = (__hip_bfloat16*)(w + 6 * F);
    __hip_bfloat16* w3k = (__hip_bfloat16*)(w + 6 * F + 294912);
    float* f1e0 = (float*)(w + 6 * F + 2 * 294912);
    float* f1e1 = f1e0 + 1048576;   // 2*2*512*512
    float* f0e0 = f1e1 + 1048576;
    float* f0e1 = f0e0 + 262144;    // 2*2*256*256

    hipLaunchKernelGGL(transpose_nhwc, dim3(16384), dim3(256), 0, stream, feat0, in0T);
    hipLaunchKernelGGL(transpose_nhwc, dim3(16384), dim3(256), 0, stream, feat2, in1T);
    hipLaunchKernelGGL(prep_w, dim3(576), dim3(256), 0, stream, wq, wk, w3q, w3k);
    hipLaunchKernelGGL(conv3x3_mfma, dim3(2048, 4), dim3(256), 0, stream,
                       in0T, in1T, w3q, w3k, bq, bk, q0, k0, q2, k2);
    hipLaunchKernelGGL(window_flow, dim3(2048, 8), dim3(256), 0, stream,
                       q0, k0, q2, k2, btab, f1e0, f1e1, f0e0, f0e1);
    hipLaunchKernelGGL(resize_out, dim3(65536), dim3(256), 0, stream,
                       f1e0, f1e1, f0e0, f0e1, (float*)d_out);
}

// Round 5
// 428.384 us; speedup vs baseline: 1.8553x; 1.0827x over previous
//
#include <hip/hip_runtime.h>
#include <hip/hip_bf16.h>
#include <math.h>

typedef __attribute__((ext_vector_type(8))) __bf16 bf16x8;
typedef __attribute__((ext_vector_type(4))) float f32x4;

#define HH 256
#define WW 256
#define SCALEF 0.08838834764831845f  // 128^-0.5

__device__ __forceinline__ void gload_lds16(const void* g, void* l) {
    __builtin_amdgcn_global_load_lds(
        (const __attribute__((address_space(1))) void*)g,
        (__attribute__((address_space(3))) void*)l, 16, 0, 0);
}

// ---------------------------------------------------------------------------
// K1: NCHW f32 -> NHWC bf16 transpose
// ---------------------------------------------------------------------------
__global__ __launch_bounds__(256) void transpose_nhwc(const float* __restrict__ in,
                                                      __hip_bfloat16* __restrict__ out)
{
    int blk = blockIdx.x;
    int c0 = (blk & 3) * 32;
    int x0 = ((blk >> 2) & 7) * 32;
    int by = blk >> 5;              // b*256 + y
    int y = by & 255, b = by >> 8;
    __shared__ float tile[32][33];
    int tx = threadIdx.x & 31, ty = threadIdx.x >> 5;   // ty 0..7
#pragma unroll
    for (int i = 0; i < 4; i++) {
        int c = c0 + ty + 8 * i;
        tile[ty + 8 * i][tx] = in[(((size_t)b * 128 + c) * HH + y) * WW + x0 + tx];
    }
    __syncthreads();
#pragma unroll
    for (int i = 0; i < 4; i++) {
        int x = x0 + ty + 8 * i;
        out[(((size_t)b * HH + y) * WW + x) * 128 + c0 + tx] =
            __float2bfloat16(tile[tx][ty + 8 * i]);
    }
}

// ---------------------------------------------------------------------------
// K2: weight repack -> chunk-major, swizzled for global_load_lds staging.
// src (co,ci,ky,kx). k_global = tap*128+ci. chunk q = k_global>>5 (32-k chunks).
// dst elem = q*4096 + co*32 + ((kin>>3) ^ ((co>>1)&3))*8 + (kin&7), kin=k_global&31
// ---------------------------------------------------------------------------
__global__ __launch_bounds__(256) void prep_w(const float* __restrict__ wq,
                                              const float* __restrict__ wk,
                                              __hip_bfloat16* __restrict__ w3q,
                                              __hip_bfloat16* __restrict__ w3k)
{
    int i = blockIdx.x * 256 + threadIdx.x;
    if (i >= 128 * 128 * 9) return;
    int co = i / (128 * 9);
    int r = i - co * 128 * 9;
    int ci = r / 9;
    int tap = r - ci * 9;
    int kg = tap * 128 + ci;
    int q = kg >> 5, kin = kg & 31;
    int slot = (kin >> 3) ^ ((co >> 1) & 3);
    int dst = q * 4096 + co * 32 + slot * 8 + (kin & 7);
    w3q[dst] = __float2bfloat16(wq[i]);
    w3k[dst] = __float2bfloat16(wk[i]);
}

// ---------------------------------------------------------------------------
// K3: conv3x3 (SAME) implicit GEMM. M=64 (8x8 px), 128 co, 4 waves (32 co each).
// A: halo patch in LDS (swizzled, unpadded 256B rows).
// B: 32-k chunks double-buffered in LDS via async global_load_lds (16B).
// Out: staged in LDS (aliases patch) -> coalesced uint4 stores.
// ---------------------------------------------------------------------------
__global__ __launch_bounds__(256, 3) void conv3x3_mfma(
    const __hip_bfloat16* __restrict__ in0, const __hip_bfloat16* __restrict__ in1,
    const __hip_bfloat16* __restrict__ w3q, const __hip_bfloat16* __restrict__ w3k,
    const float* __restrict__ bq, const float* __restrict__ bk,
    __hip_bfloat16* __restrict__ q0, __hip_bfloat16* __restrict__ k0,
    __hip_bfloat16* __restrict__ q2, __hip_bfloat16* __restrict__ k2)
{
    const int cid = blockIdx.y;
    const __hip_bfloat16* src = (cid >= 2) ? in1 : in0;
    const __hip_bfloat16* wmat = (cid & 1) ? w3k : w3q;
    const float* bias = (cid & 1) ? bk : bq;
    __hip_bfloat16* dst = (cid == 0) ? q0 : (cid == 1) ? k0 : (cid == 2) ? q2 : k2;

    const int blk = blockIdx.x;           // 0..2047
    const int b = blk >> 10;
    const int rr = blk & 1023;
    const int y0 = (rr >> 5) << 3;
    const int x0 = (rr & 31) << 3;

    __shared__ __align__(16) char smem[25600 + 16384];   // patch 100*256B + B dbuf 2*8KB
    char* patch = smem;
    char* ldsB = smem + 25600;

    const int tid = threadIdx.x;

    // ---- stage input halo patch (swizzled 16B slots) ----
    for (int idx = tid; idx < 1600; idx += 256) {
        int p = idx >> 4, lc = idx & 15;
        int py = p / 10, px = p - py * 10;
        int gy = y0 + py - 1, gx = x0 + px - 1;
        uint4 v = make_uint4(0u, 0u, 0u, 0u);
        if (gy >= 0 && gy < HH && gx >= 0 && gx < WW)
            v = *(const uint4*)(src + ((((size_t)b * HH + gy) * WW + gx) << 7) + lc * 8);
        *(uint4*)(patch + p * 256 + ((lc ^ (p & 7)) << 4)) = v;
    }
    // ---- async-stage B chunk 0 into buf 0 ----
    {
        const char* s = (const char*)wmat + tid * 16;
        char* dl = ldsB + tid * 16;
        gload_lds16(s, dl);
        gload_lds16(s + 4096, dl + 4096);
    }
    __syncthreads();

    const int lane = tid & 63;
    const int wv = tid >> 6;
    const int l15 = lane & 15;
    const int kq = lane >> 4;
    const int myb = l15 >> 3, mxb = l15 & 7;
    const int c0 = wv * 32 + l15;
    const int c1 = c0 + 16;
    const int bswz = ((kq ^ ((l15 >> 1) & 3)) << 4);
    const int bO0 = c0 * 64 + bswz;
    const int bO1 = c1 * 64 + bswz;

    f32x4 acc[4][2];
#pragma unroll
    for (int mi = 0; mi < 4; mi++)
#pragma unroll
        for (int n = 0; n < 2; n++) acc[mi][n] = (f32x4){0.f, 0.f, 0.f, 0.f};

#pragma unroll
    for (int t = 0; t < 9; ++t) {
        const int ky = t / 3, kx = t - ky * 3;
#pragma unroll
        for (int cc = 0; cc < 4; ++cc) {
            const int q = t * 4 + cc;
            if (q + 1 < 36) {                 // async prefetch next chunk
                const char* s = (const char*)wmat + (size_t)(q + 1) * 8192 + tid * 16;
                char* dl = ldsB + ((q + 1) & 1) * 8192 + tid * 16;
                gload_lds16(s, dl);
                gload_lds16(s + 4096, dl + 4096);
            }
            const char* bb = ldsB + (q & 1) * 8192;
            bf16x8 b0 = *(const bf16x8*)(bb + bO0);
            bf16x8 b1 = *(const bf16x8*)(bb + bO1);
            const int slot = cc * 4 + kq;
#pragma unroll
            for (int mi = 0; mi < 4; ++mi) {
                int pos = (mi * 2 + myb + ky) * 10 + (mxb + kx);
                bf16x8 a = *(const bf16x8*)(patch + pos * 256 + ((slot ^ (pos & 7)) << 4));
                acc[mi][0] = __builtin_amdgcn_mfma_f32_16x16x32_bf16(a, b0, acc[mi][0], 0, 0, 0);
                acc[mi][1] = __builtin_amdgcn_mfma_f32_16x16x32_bf16(a, b1, acc[mi][1], 0, 0, 0);
            }
            __syncthreads();
        }
    }

    // ---- epilogue: bias, stage in LDS (aliases patch), coalesced store ----
    float bv0 = bias[c0];
    float bv1 = bias[c1];
    __hip_bfloat16* stage = (__hip_bfloat16*)patch;   // [64 px][stride 136 el]
#pragma unroll
    for (int mi = 0; mi < 4; ++mi) {
#pragma unroll
        for (int r = 0; r < 4; ++r) {
            int m = mi * 16 + kq * 4 + r;
            stage[m * 136 + c0] = __float2bfloat16(acc[mi][0][r] + bv0);
            stage[m * 136 + c1] = __float2bfloat16(acc[mi][1][r] + bv1);
        }
    }
    __syncthreads();

#pragma unroll
    for (int it = 0; it < 4; ++it) {
        int idx = it * 256 + tid;
        int p = idx >> 4, lc = idx & 15;
        int y = y0 + (p >> 3), x = x0 + (p & 7);
        uint4 v = *(const uint4*)((const char*)patch + p * 272 + lc * 16);
        *(uint4*)(dst + ((((size_t)b * HH + y) * WW + x) << 7) + lc * 8) = v;
    }
}

// ---------------------------------------------------------------------------
// K4: per-(window, estimate x shift) correlation + flow_bsd + flow_mid.
// cls aliases qt/kt (dead after MFMA) -> 36.7 KB LDS -> 4 blocks/CU.
// Grid flattened 16384; decode keeps a window's 8 combos on one XCD,
// temporally adjacent (L2 reuse of the window's q/k data).
// ---------------------------------------------------------------------------
#define WPAD 136     // 272B rows: 2-way banks (free)
#define CST 66       // cls row stride (floats)
__global__ __launch_bounds__(256, 4) void window_flow(
    const __hip_bfloat16* __restrict__ q0, const __hip_bfloat16* __restrict__ k0,
    const __hip_bfloat16* __restrict__ q2, const __hip_bfloat16* __restrict__ k2,
    const float* __restrict__ btab,
    float* __restrict__ f1e0, float* __restrict__ f1e1,
    float* __restrict__ f0e0, float* __restrict__ f0e1)
{
    const int id = blockIdx.x;               // 0..16383
    const int xcd = id & 7;
    const int slot = id >> 3;
    const int combo = slot & 7;               // 8 combos adjacent on one XCD
    const int wdx = (slot >> 3) * 8 + xcd;    // 0..2047

    const int e = combo >> 2;
    const int sflag = combo & 3;
    const int shq = (sflag >> 1) & 1;        // shift_h flag == quadrant y
    const int swq = sflag & 1;               // shift_w flag == quadrant x
    const int sh = shq ? 4 : 0, sw = swq ? 4 : 0;
    const __hip_bfloat16* qf = e ? q2 : q0;
    const __hip_bfloat16* kf = e ? k0 : k2;
    float* f1 = e ? f1e1 : f1e0;
    float* f0 = e ? f0e1 : f0e0;

    const int b = wdx >> 10;
    const int s1i = (wdx >> 5) & 31;
    const int s2i = wdx & 31;

    __shared__ __align__(16) char wsm[64 * WPAD * 2 * 2];   // 34816 B
    __hip_bfloat16* qt = (__hip_bfloat16*)wsm;
    __hip_bfloat16* kt = (__hip_bfloat16*)(wsm + 64 * WPAD * 2);
    float* cls = (float*)wsm;                 // aliases qt/kt after MFMA phase
    __shared__ float cmid[81], fxm[81], fym[81];
    __shared__ float sb[225];

    const int tid = threadIdx.x;
    if (tid < 225) sb[tid] = btab[tid];

    for (int idx = tid; idx < 2048; idx += 256) {
        int which = idx >> 10;
        int p = (idx >> 4) & 63, lc = idx & 15;
        int iy = p >> 3, ix = p & 7;
        int gy = (s1i * 8 + iy + sh) & 255;
        int gx = (s2i * 8 + ix + sw) & 255;
        const __hip_bfloat16* srcf = which ? kf : qf;
        uint4 v = *(const uint4*)(srcf + ((((size_t)b * HH + gy) * WW + gx) << 7) + lc * 8);
        __hip_bfloat16* dstt = which ? kt : qt;
        *(uint4*)(dstt + p * WPAD + lc * 8) = v;
    }
    __syncthreads();

    // corr = qw . kw^T   (M=64, N=64, K=128), 4 waves over M
    const int lane = tid & 63;
    const int wv = tid >> 6;
    const int l15 = lane & 15;
    const int kq = lane >> 4;

    f32x4 acc[4];
#pragma unroll
    for (int nf = 0; nf < 4; nf++) acc[nf] = (f32x4){0.f, 0.f, 0.f, 0.f};

#pragma unroll
    for (int kc = 0; kc < 4; ++kc) {
        bf16x8 a = *(const bf16x8*)(qt + (wv * 16 + l15) * WPAD + kc * 32 + kq * 8);
#pragma unroll
        for (int nf = 0; nf < 4; ++nf) {
            bf16x8 bb = *(const bf16x8*)(kt + (nf * 16 + l15) * WPAD + kc * 32 + kq * 8);
            acc[nf] = __builtin_amdgcn_mfma_f32_16x16x32_bf16(a, bb, acc[nf], 0, 0, 0);
        }
    }
    __syncthreads();   // qt/kt reads complete before cls overwrites them

    // epilogue: scale + relative-pos bias + shift mask -> cls
#pragma unroll
    for (int nf = 0; nf < 4; ++nf) {
#pragma unroll
        for (int r = 0; r < 4; ++r) {
            int row = wv * 16 + kq * 4 + r;
            int col = nf * 16 + l15;
            int qy = row >> 3, qx = row & 7;
            int ty = col >> 3, tx = col & 7;
            float v = acc[nf][r] * SCALEF + sb[(qy - ty + 7) * 15 + (qx - tx + 7)];
            if (sflag) {
                int rhq = 0, rwq = 0, rht = 0, rwt = 0;
                if (shq && s1i == 31) { rhq = (qy < 4) ? 1 : 2; rht = (ty < 4) ? 1 : 2; }
                if (swq && s2i == 31) { rwq = (qx < 4) ? 1 : 2; rwt = (tx < 4) ? 1 : 2; }
                int regq, regt;
                if (shq && swq) { regq = rhq * 3 + rwq; regt = rht * 3 + rwt; }
                else if (shq)   { regq = rhq; regt = rht; }
                else            { regq = rwq; regt = rwt; }
                if (regq != regt) v -= 10000.0f;
            }
            cls[row * CST + col] = v;
        }
    }
    __syncthreads();

    const int rg = tid >> 4;       // 16 row-groups
    const int lg = tid & 15;       // 16 lanes per row

    // ---- flow_bsd: 16 rows, one 16-lane group each, 4 consecutive cols/lane ----
    {
        int fy = rg >> 2, fx = rg & 3;
        int qy = fy + 2, qx = fx + 2;
        const float* rowp = &cls[(qy * 8 + qx) * CST];
        float v[4];
        float mx = -1e30f;
#pragma unroll
        for (int j = 0; j < 4; ++j) { v[j] = rowp[lg * 4 + j]; mx = fmaxf(mx, v[j]); }
#pragma unroll
        for (int m = 8; m >= 1; m >>= 1) mx = fmaxf(mx, __shfl_xor(mx, m));
        float S = 0.f, sx = 0.f, sy = 0.f;
#pragma unroll
        for (int j = 0; j < 4; ++j) {
            int t = lg * 4 + j;
            float p = __expf(v[j] - mx);
            S += p; sx += p * (float)(t & 7); sy += p * (float)(t >> 3);
        }
#pragma unroll
        for (int m = 8; m >= 1; m >>= 1) {
            S += __shfl_xor(S, m); sx += __shfl_xor(sx, m); sy += __shfl_xor(sy, m);
        }
        if (lg == 0) {
            float fxv = sx / S - (float)qx;
            float fyv = sy / S - (float)qy;
            int Y = (s1i * 8 + shq * 4 + fy + 2) & 255;
            int X = (s2i * 8 + swq * 4 + fx + 2) & 255;
            size_t base = (size_t)b * 2 * HH * WW;
            f0[base + (size_t)Y * WW + X] = fxv;
            f0[base + (size_t)HH * WW + (size_t)Y * WW + X] = fyv;
        }
    }

    // ---- flow_mid row softmaxes: 81 rows, 16 at a time ----
    for (int it = 0; it < 6; ++it) {
        int rm = it * 16 + rg;
        if (rm < 81) {
            int a = rm / 9, bc = rm - a * 9;
            float v[4];
            float mx = -1e30f;
#pragma unroll
            for (int j = 0; j < 4; ++j) {
                int t = lg + 16 * j;
                int h2 = t >> 3, w2 = t & 7;
                int qy = a + 3 - h2, qx = bc + 3 - w2;
                v[j] = ((unsigned)qy < 8u && (unsigned)qx < 8u) ? cls[(qy * 8 + qx) * CST + t] : 0.0f;
                mx = fmaxf(mx, v[j]);
            }
#pragma unroll
            for (int m = 8; m >= 1; m >>= 1) mx = fmaxf(mx, __shfl_xor(mx, m));
            float S = 0.f, sc = 0.f, sx = 0.f, sy = 0.f;
#pragma unroll
            for (int j = 0; j < 4; ++j) {
                int t = lg + 16 * j;
                float p = __expf(v[j] - mx);
                S += p; sc += v[j] * p; sx += p * (float)(t & 7); sy += p * (float)(t >> 3);
            }
#pragma unroll
            for (int m = 8; m >= 1; m >>= 1) {
                S += __shfl_xor(S, m); sc += __shfl_xor(sc, m);
                sx += __shfl_xor(sx, m); sy += __shfl_xor(sy, m);
            }
            if (lg == 0) {
                float inv = 1.0f / S;
                cmid[rm] = sc * inv;
                fxm[rm] = sx * inv - (float)(bc + 3) * 0.5f;
                fym[rm] = sy * inv - (float)(a + 3) * 0.5f;
            }
        }
    }
    __syncthreads();

    // flow_mid quadrant combine -> 8x8
    if (tid < 64) {
        int fy = tid >> 3, fx = tid & 7;
        int i00 = fy * 9 + fx, i01 = i00 + 1, i10 = i00 + 9, i11 = i00 + 10;
        float c00 = cmid[i00], c01 = cmid[i01], c10 = cmid[i10], c11 = cmid[i11];
        float m = fmaxf(fmaxf(c00, c01), fmaxf(c10, c11));
        float p0 = __expf(c00 - m), p1 = __expf(c01 - m), p2 = __expf(c10 - m), p3 = __expf(c11 - m);
        float S = p0 + p1 + p2 + p3;
        float ox = 2.0f * (p0 * fxm[i00] + p1 * fxm[i01] + p2 * fxm[i10] + p3 * fxm[i11]) / S;
        float oy = 2.0f * (p0 * fym[i00] + p1 * fym[i01] + p2 * fym[i10] + p3 * fym[i11]) / S;
        int Y = (s1i * 16 + shq * 8 + fy + 4) & 511;
        int X = (s2i * 16 + swq * 8 + fx + 4) & 511;
        size_t base = (size_t)b * 2 * 512 * 512;
        f1[base + (size_t)Y * 512 + X] = ox;
        f1[base + (size_t)512 * 512 + (size_t)Y * 512 + X] = oy;
    }
}

// ---------------------------------------------------------------------------
// K5: bilinear resize (half-pixel, edge clamp) + scale, concat 4 outputs
// ---------------------------------------------------------------------------
__global__ __launch_bounds__(256) void resize_out(
    const float* __restrict__ f1e0, const float* __restrict__ f1e1,
    const float* __restrict__ f0e0, const float* __restrict__ f0e1,
    float* __restrict__ out)
{
    int idx = blockIdx.x * 256 + threadIdx.x;       // 0 .. 16777215
    int o = idx >> 22;
    int rem = idx & 4194303;
    int bc = rem >> 20;                              // b*2+ch
    int Y = (rem >> 10) & 1023;
    int X = rem & 1023;
    const float* src; int n; float invf, sc;
    if (o == 0)      { src = f1e1; n = 512; invf = 0.5f;  sc = 2.f; }
    else if (o == 1) { src = f1e0; n = 512; invf = 0.5f;  sc = 2.f; }
    else if (o == 2) { src = f0e0; n = 256; invf = 0.25f; sc = 4.f; }
    else             { src = f0e1; n = 256; invf = 0.25f; sc = 4.f; }
    float syf = ((float)Y + 0.5f) * invf - 0.5f;
    float sxf = ((float)X + 0.5f) * invf - 0.5f;
    int iy = (int)floorf(syf), ix = (int)floorf(sxf);
    float wy = syf - (float)iy, wx = sxf - (float)ix;
    int y0c = min(max(iy, 0), n - 1), y1c = min(max(iy + 1, 0), n - 1);
    int x0c = min(max(ix, 0), n - 1), x1c = min(max(ix + 1, 0), n - 1);
    const float* s = src + (size_t)bc * n * n;
    float v00 = s[(size_t)y0c * n + x0c], v01 = s[(size_t)y0c * n + x1c];
    float v10 = s[(size_t)y1c * n + x0c], v11 = s[(size_t)y1c * n + x1c];
    float v = (1.f - wy) * ((1.f - wx) * v00 + wx * v01) + wy * ((1.f - wx) * v10 + wx * v11);
    out[idx] = v * sc;
}

// ---------------------------------------------------------------------------
extern "C" void kernel_launch(void* const* d_in, const int* in_sizes, int n_in,
                              void* d_out, int out_size, void* d_ws, size_t ws_size,
                              hipStream_t stream)
{
    const float* feat0 = (const float*)d_in[0];
    const float* feat2 = (const float*)d_in[1];
    const float* wq = (const float*)d_in[2];
    const float* bq = (const float*)d_in[3];
    const float* wk = (const float*)d_in[4];
    const float* bk = (const float*)d_in[5];
    const float* btab = (const float*)d_in[6];

    char* w = (char*)d_ws;
    const size_t F = (size_t)16777216 * 2;   // bytes per bf16 NHWC field (2*256*256*128)
    __hip_bfloat16* q0 = (__hip_bfloat16*)(w);
    __hip_bfloat16* k0 = (__hip_bfloat16*)(w + F);
    __hip_bfloat16* q2 = (__hip_bfloat16*)(w + 2 * F);
    __hip_bfloat16* k2 = (__hip_bfloat16*)(w + 3 * F);
    __hip_bfloat16* in0T = (__hip_bfloat16*)(w + 4 * F);
    __hip_bfloat16* in1T = (__hip_bfloat16*)(w + 5 * F);
    __hip_bfloat16* w3q = (__hip_bfloat16*)(w + 6 * F);
    __hip_bfloat16* w3k = (__hip_bfloat16*)(w + 6 * F + 294912);
    float* f1e0 = (float*)(w + 6 * F + 2 * 294912);
    float* f1e1 = f1e0 + 1048576;   // 2*2*512*512
    float* f0e0 = f1e1 + 1048576;
    float* f0e1 = f0e0 + 262144;    // 2*2*256*256

    hipLaunchKernelGGL(transpose_nhwc, dim3(16384), dim3(256), 0, stream, feat0, in0T);
    hipLaunchKernelGGL(transpose_nhwc, dim3(16384), dim3(256), 0, stream, feat2, in1T);
    hipLaunchKernelGGL(prep_w, dim3(576), dim3(256), 0, stream, wq, wk, w3q, w3k);
    hipLaunchKernelGGL(conv3x3_mfma, dim3(2048, 4), dim3(256), 0, stream,
                       in0T, in1T, w3q, w3k, bq, bk, q0, k0, q2, k2);
    hipLaunchKernelGGL(window_flow, dim3(16384), dim3(256), 0, stream,
                       q0, k0, q2, k2, btab, f1e0, f1e1, f0e0, f0e1);
    hipLaunchKernelGGL(resize_out, dim3(65536), dim3(256), 0, stream,
                       f1e0, f1e1, f0e0, f0e1, (float*)d_out);
}

// Round 6
// 421.828 us; speedup vs baseline: 1.8842x; 1.0155x over previous
//
#include <hip/hip_runtime.h>
#include <hip/hip_bf16.h>
#include <math.h>

typedef __attribute__((ext_vector_type(8))) __bf16 bf16x8;
typedef __attribute__((ext_vector_type(4))) float f32x4;

#define HH 256
#define WW 256
#define SCALEF 0.08838834764831845f  // 128^-0.5

__device__ __forceinline__ void gload_lds16(const void* g, void* l) {
    __builtin_amdgcn_global_load_lds(
        (const __attribute__((address_space(1))) void*)g,
        (__attribute__((address_space(3))) void*)l, 16, 0, 0);
}

// ---------------------------------------------------------------------------
// K1: NCHW f32 -> NHWC bf16 transpose
// ---------------------------------------------------------------------------
__global__ __launch_bounds__(256) void transpose_nhwc(const float* __restrict__ in,
                                                      __hip_bfloat16* __restrict__ out)
{
    int blk = blockIdx.x;
    int c0 = (blk & 3) * 32;
    int x0 = ((blk >> 2) & 7) * 32;
    int by = blk >> 5;              // b*256 + y
    int y = by & 255, b = by >> 8;
    __shared__ float tile[32][33];
    int tx = threadIdx.x & 31, ty = threadIdx.x >> 5;   // ty 0..7
#pragma unroll
    for (int i = 0; i < 4; i++) {
        int c = c0 + ty + 8 * i;
        tile[ty + 8 * i][tx] = in[(((size_t)b * 128 + c) * HH + y) * WW + x0 + tx];
    }
    __syncthreads();
#pragma unroll
    for (int i = 0; i < 4; i++) {
        int x = x0 + ty + 8 * i;
        out[(((size_t)b * HH + y) * WW + x) * 128 + c0 + tx] =
            __float2bfloat16(tile[tx][ty + 8 * i]);
    }
}

// ---------------------------------------------------------------------------
// K2: weight repack -> chunk-major, swizzled for global_load_lds staging.
// src (co,ci,ky,kx). k_global = tap*128+ci. chunk q = k_global>>5 (32-k chunks).
// dst elem = q*4096 + co*32 + ((kin>>3) ^ ((co>>1)&3))*8 + (kin&7), kin=k_global&31
// ---------------------------------------------------------------------------
__global__ __launch_bounds__(256) void prep_w(const float* __restrict__ wq,
                                              const float* __restrict__ wk,
                                              __hip_bfloat16* __restrict__ w3q,
                                              __hip_bfloat16* __restrict__ w3k)
{
    int i = blockIdx.x * 256 + threadIdx.x;
    if (i >= 128 * 128 * 9) return;
    int co = i / (128 * 9);
    int r = i - co * 128 * 9;
    int ci = r / 9;
    int tap = r - ci * 9;
    int kg = tap * 128 + ci;
    int q = kg >> 5, kin = kg & 31;
    int slot = (kin >> 3) ^ ((co >> 1) & 3);
    int dst = q * 4096 + co * 32 + slot * 8 + (kin & 7);
    w3q[dst] = __float2bfloat16(wq[i]);
    w3k[dst] = __float2bfloat16(wk[i]);
}

// ---------------------------------------------------------------------------
// K3: conv3x3 (SAME) implicit GEMM. M=64 (8x8 px), 128 co, 4 waves (32 co each).
// A: halo patch in LDS (swizzled, unpadded 256B rows).
// B: 32-k chunks TRIPLE-buffered via async global_load_lds (16B), prefetch
//    distance 2, counted vmcnt(2) + raw s_barrier in the K-loop (never drain
//    to 0 mid-loop) -- T3/T4 pattern.
// Out: staged in LDS (aliases patch) -> coalesced uint4 stores.
// ---------------------------------------------------------------------------
__global__ __launch_bounds__(256, 3) void conv3x3_mfma(
    const __hip_bfloat16* __restrict__ in0, const __hip_bfloat16* __restrict__ in1,
    const __hip_bfloat16* __restrict__ w3q, const __hip_bfloat16* __restrict__ w3k,
    const float* __restrict__ bq, const float* __restrict__ bk,
    __hip_bfloat16* __restrict__ q0, __hip_bfloat16* __restrict__ k0,
    __hip_bfloat16* __restrict__ q2, __hip_bfloat16* __restrict__ k2)
{
    const int cid = blockIdx.y;
    const __hip_bfloat16* src = (cid >= 2) ? in1 : in0;
    const __hip_bfloat16* wmat = (cid & 1) ? w3k : w3q;
    const float* bias = (cid & 1) ? bk : bq;
    __hip_bfloat16* dst = (cid == 0) ? q0 : (cid == 1) ? k0 : (cid == 2) ? q2 : k2;

    const int blk = blockIdx.x;           // 0..2047
    const int b = blk >> 10;
    const int rr = blk & 1023;
    const int y0 = (rr >> 5) << 3;
    const int x0 = (rr & 31) << 3;

    __shared__ __align__(16) char smem[25600 + 24576];   // patch 100*256B + B 3x8KB
    char* patch = smem;
    char* ldsB = smem + 25600;

    const int tid = threadIdx.x;

    // ---- stage input halo patch (swizzled 16B slots) ----
    for (int idx = tid; idx < 1600; idx += 256) {
        int p = idx >> 4, lc = idx & 15;
        int py = p / 10, px = p - py * 10;
        int gy = y0 + py - 1, gx = x0 + px - 1;
        uint4 v = make_uint4(0u, 0u, 0u, 0u);
        if (gy >= 0 && gy < HH && gx >= 0 && gx < WW)
            v = *(const uint4*)(src + ((((size_t)b * HH + gy) * WW + gx) << 7) + lc * 8);
        *(uint4*)(patch + p * 256 + ((lc ^ (p & 7)) << 4)) = v;
    }
    // ---- async-stage B chunks 0,1 into buf 0,1 ----
    {
        const char* s = (const char*)wmat + tid * 16;
        char* dl = ldsB + tid * 16;
        gload_lds16(s, dl);
        gload_lds16(s + 4096, dl + 4096);
        gload_lds16(s + 8192, dl + 8192);
        gload_lds16(s + 12288, dl + 12288);
    }
    __syncthreads();   // full drain once (patch + chunks 0,1 ready)

    const int lane = tid & 63;
    const int wv = tid >> 6;
    const int l15 = lane & 15;
    const int kq = lane >> 4;
    const int myb = l15 >> 3, mxb = l15 & 7;
    const int c0 = wv * 32 + l15;
    const int c1 = c0 + 16;
    const int bswz = ((kq ^ ((l15 >> 1) & 3)) << 4);
    const int bO0 = c0 * 64 + bswz;
    const int bO1 = c1 * 64 + bswz;

    f32x4 acc[4][2];
#pragma unroll
    for (int mi = 0; mi < 4; mi++)
#pragma unroll
        for (int n = 0; n < 2; n++) acc[mi][n] = (f32x4){0.f, 0.f, 0.f, 0.f};

#pragma unroll
    for (int q = 0; q < 36; ++q) {
        const int t = q >> 2, cc = q & 3;
        const int ky = t / 3, kx = t - ky * 3;
        if (q + 2 < 36) {                 // prefetch distance 2 -> buf[(q+2)%3]
            const char* s = (const char*)wmat + (size_t)(q + 2) * 8192 + tid * 16;
            char* dl = ldsB + ((q + 2) % 3) * 8192 + tid * 16;
            gload_lds16(s, dl);
            gload_lds16(s + 4096, dl + 4096);
        }
        const char* bb = ldsB + (q % 3) * 8192;
        bf16x8 b0 = *(const bf16x8*)(bb + bO0);
        bf16x8 b1 = *(const bf16x8*)(bb + bO1);
        const int slot = cc * 4 + kq;
#pragma unroll
        for (int mi = 0; mi < 4; ++mi) {
            int pos = (mi * 2 + myb + ky) * 10 + (mxb + kx);
            bf16x8 a = *(const bf16x8*)(patch + pos * 256 + ((slot ^ (pos & 7)) << 4));
            acc[mi][0] = __builtin_amdgcn_mfma_f32_16x16x32_bf16(a, b0, acc[mi][0], 0, 0, 0);
            acc[mi][1] = __builtin_amdgcn_mfma_f32_16x16x32_bf16(a, b1, acc[mi][1], 0, 0, 0);
        }
        if (q + 1 < 36) {
            // counted wait: chunk q+1's 2 DMA ops must land; q+2's 2 stay in flight
            if (q + 2 < 36) asm volatile("s_waitcnt vmcnt(2)" ::: "memory");
            else            asm volatile("s_waitcnt vmcnt(0)" ::: "memory");
            __builtin_amdgcn_s_barrier();
            __builtin_amdgcn_sched_barrier(0);
        }
    }
    __syncthreads();   // all patch/B reads done before stage overwrite

    // ---- epilogue: bias, stage in LDS (aliases patch), coalesced store ----
    float bv0 = bias[c0];
    float bv1 = bias[c1];
    __hip_bfloat16* stage = (__hip_bfloat16*)patch;   // [64 px][stride 136 el]
#pragma unroll
    for (int mi = 0; mi < 4; ++mi) {
#pragma unroll
        for (int r = 0; r < 4; ++r) {
            int m = mi * 16 + kq * 4 + r;
            stage[m * 136 + c0] = __float2bfloat16(acc[mi][0][r] + bv0);
            stage[m * 136 + c1] = __float2bfloat16(acc[mi][1][r] + bv1);
        }
    }
    __syncthreads();

#pragma unroll
    for (int it = 0; it < 4; ++it) {
        int idx = it * 256 + tid;
        int p = idx >> 4, lc = idx & 15;
        int y = y0 + (p >> 3), x = x0 + (p & 7);
        uint4 v = *(const uint4*)((const char*)patch + p * 272 + lc * 16);
        *(uint4*)(dst + ((((size_t)b * HH + y) * WW + x) << 7) + lc * 8) = v;
    }
}

// ---------------------------------------------------------------------------
// K4: per-(window, estimate x shift) correlation + flow_bsd + flow_mid.
// cls aliases qt/kt (dead after MFMA) -> 36.7 KB LDS -> 4 blocks/CU.
// Grid flattened 16384; decode keeps a window's 8 combos on one XCD,
// temporally adjacent (L2 reuse of the window's q/k data).
// ---------------------------------------------------------------------------
#define WPAD 136     // 272B rows: 2-way banks (free)
#define CST 66       // cls row stride (floats)
__global__ __launch_bounds__(256, 4) void window_flow(
    const __hip_bfloat16* __restrict__ q0, const __hip_bfloat16* __restrict__ k0,
    const __hip_bfloat16* __restrict__ q2, const __hip_bfloat16* __restrict__ k2,
    const float* __restrict__ btab,
    float* __restrict__ f1e0, float* __restrict__ f1e1,
    float* __restrict__ f0e0, float* __restrict__ f0e1)
{
    const int id = blockIdx.x;               // 0..16383
    const int xcd = id & 7;
    const int slot = id >> 3;
    const int combo = slot & 7;               // 8 combos adjacent on one XCD
    const int wdx = (slot >> 3) * 8 + xcd;    // 0..2047

    const int e = combo >> 2;
    const int sflag = combo & 3;
    const int shq = (sflag >> 1) & 1;        // shift_h flag == quadrant y
    const int swq = sflag & 1;               // shift_w flag == quadrant x
    const int sh = shq ? 4 : 0, sw = swq ? 4 : 0;
    const __hip_bfloat16* qf = e ? q2 : q0;
    const __hip_bfloat16* kf = e ? k0 : k2;
    float* f1 = e ? f1e1 : f1e0;
    float* f0 = e ? f0e1 : f0e0;

    const int b = wdx >> 10;
    const int s1i = (wdx >> 5) & 31;
    const int s2i = wdx & 31;

    __shared__ __align__(16) char wsm[64 * WPAD * 2 * 2];   // 34816 B
    __hip_bfloat16* qt = (__hip_bfloat16*)wsm;
    __hip_bfloat16* kt = (__hip_bfloat16*)(wsm + 64 * WPAD * 2);
    float* cls = (float*)wsm;                 // aliases qt/kt after MFMA phase
    __shared__ float cmid[81], fxm[81], fym[81];
    __shared__ float sb[225];

    const int tid = threadIdx.x;
    if (tid < 225) sb[tid] = btab[tid];

    for (int idx = tid; idx < 2048; idx += 256) {
        int which = idx >> 10;
        int p = (idx >> 4) & 63, lc = idx & 15;
        int iy = p >> 3, ix = p & 7;
        int gy = (s1i * 8 + iy + sh) & 255;
        int gx = (s2i * 8 + ix + sw) & 255;
        const __hip_bfloat16* srcf = which ? kf : qf;
        uint4 v = *(const uint4*)(srcf + ((((size_t)b * HH + gy) * WW + gx) << 7) + lc * 8);
        __hip_bfloat16* dstt = which ? kt : qt;
        *(uint4*)(dstt + p * WPAD + lc * 8) = v;
    }
    __syncthreads();

    // corr = qw . kw^T   (M=64, N=64, K=128), 4 waves over M
    const int lane = tid & 63;
    const int wv = tid >> 6;
    const int l15 = lane & 15;
    const int kq = lane >> 4;

    f32x4 acc[4];
#pragma unroll
    for (int nf = 0; nf < 4; nf++) acc[nf] = (f32x4){0.f, 0.f, 0.f, 0.f};

#pragma unroll
    for (int kc = 0; kc < 4; ++kc) {
        bf16x8 a = *(const bf16x8*)(qt + (wv * 16 + l15) * WPAD + kc * 32 + kq * 8);
#pragma unroll
        for (int nf = 0; nf < 4; ++nf) {
            bf16x8 bb = *(const bf16x8*)(kt + (nf * 16 + l15) * WPAD + kc * 32 + kq * 8);
            acc[nf] = __builtin_amdgcn_mfma_f32_16x16x32_bf16(a, bb, acc[nf], 0, 0, 0);
        }
    }
    __syncthreads();   // qt/kt reads complete before cls overwrites them

    // epilogue: scale + relative-pos bias + shift mask -> cls
#pragma unroll
    for (int nf = 0; nf < 4; ++nf) {
#pragma unroll
        for (int r = 0; r < 4; ++r) {
            int row = wv * 16 + kq * 4 + r;
            int col = nf * 16 + l15;
            int qy = row >> 3, qx = row & 7;
            int ty = col >> 3, tx = col & 7;
            float v = acc[nf][r] * SCALEF + sb[(qy - ty + 7) * 15 + (qx - tx + 7)];
            if (sflag) {
                int rhq = 0, rwq = 0, rht = 0, rwt = 0;
                if (shq && s1i == 31) { rhq = (qy < 4) ? 1 : 2; rht = (ty < 4) ? 1 : 2; }
                if (swq && s2i == 31) { rwq = (qx < 4) ? 1 : 2; rwt = (tx < 4) ? 1 : 2; }
                int regq, regt;
                if (shq && swq) { regq = rhq * 3 + rwq; regt = rht * 3 + rwt; }
                else if (shq)   { regq = rhq; regt = rht; }
                else            { regq = rwq; regt = rwt; }
                if (regq != regt) v -= 10000.0f;
            }
            cls[row * CST + col] = v;
        }
    }
    __syncthreads();

    const int rg = tid >> 4;       // 16 row-groups
    const int lg = tid & 15;       // 16 lanes per row

    // ---- flow_bsd: 16 rows, one 16-lane group each, 4 consecutive cols/lane ----
    {
        int fy = rg >> 2, fx = rg & 3;
        int qy = fy + 2, qx = fx + 2;
        const float* rowp = &cls[(qy * 8 + qx) * CST];
        float v[4];
        float mx = -1e30f;
#pragma unroll
        for (int j = 0; j < 4; ++j) { v[j] = rowp[lg * 4 + j]; mx = fmaxf(mx, v[j]); }
#pragma unroll
        for (int m = 8; m >= 1; m >>= 1) mx = fmaxf(mx, __shfl_xor(mx, m));
        float S = 0.f, sx = 0.f, sy = 0.f;
#pragma unroll
        for (int j = 0; j < 4; ++j) {
            int t = lg * 4 + j;
            float p = __expf(v[j] - mx);
            S += p; sx += p * (float)(t & 7); sy += p * (float)(t >> 3);
        }
#pragma unroll
        for (int m = 8; m >= 1; m >>= 1) {
            S += __shfl_xor(S, m); sx += __shfl_xor(sx, m); sy += __shfl_xor(sy, m);
        }
        if (lg == 0) {
            float fxv = sx / S - (float)qx;
            float fyv = sy / S - (float)qy;
            int Y = (s1i * 8 + shq * 4 + fy + 2) & 255;
            int X = (s2i * 8 + swq * 4 + fx + 2) & 255;
            size_t base = (size_t)b * 2 * HH * WW;
            f0[base + (size_t)Y * WW + X] = fxv;
            f0[base + (size_t)HH * WW + (size_t)Y * WW + X] = fyv;
        }
    }

    // ---- flow_mid row softmaxes: 81 rows, 16 at a time ----
    for (int it = 0; it < 6; ++it) {
        int rm = it * 16 + rg;
        if (rm < 81) {
            int a = rm / 9, bc = rm - a * 9;
            float v[4];
            float mx = -1e30f;
#pragma unroll
            for (int j = 0; j < 4; ++j) {
                int t = lg + 16 * j;
                int h2 = t >> 3, w2 = t & 7;
                int qy = a + 3 - h2, qx = bc + 3 - w2;
                v[j] = ((unsigned)qy < 8u && (unsigned)qx < 8u) ? cls[(qy * 8 + qx) * CST + t] : 0.0f;
                mx = fmaxf(mx, v[j]);
            }
#pragma unroll
            for (int m = 8; m >= 1; m >>= 1) mx = fmaxf(mx, __shfl_xor(mx, m));
            float S = 0.f, sc = 0.f, sx = 0.f, sy = 0.f;
#pragma unroll
            for (int j = 0; j < 4; ++j) {
                int t = lg + 16 * j;
                float p = __expf(v[j] - mx);
                S += p; sc += v[j] * p; sx += p * (float)(t & 7); sy += p * (float)(t >> 3);
            }
#pragma unroll
            for (int m = 8; m >= 1; m >>= 1) {
                S += __shfl_xor(S, m); sc += __shfl_xor(sc, m);
                sx += __shfl_xor(sx, m); sy += __shfl_xor(sy, m);
            }
            if (lg == 0) {
                float inv = 1.0f / S;
                cmid[rm] = sc * inv;
                fxm[rm] = sx * inv - (float)(bc + 3) * 0.5f;
                fym[rm] = sy * inv - (float)(a + 3) * 0.5f;
            }
        }
    }
    __syncthreads();

    // flow_mid quadrant combine -> 8x8
    if (tid < 64) {
        int fy = tid >> 3, fx = tid & 7;
        int i00 = fy * 9 + fx, i01 = i00 + 1, i10 = i00 + 9, i11 = i00 + 10;
        float c00 = cmid[i00], c01 = cmid[i01], c10 = cmid[i10], c11 = cmid[i11];
        float m = fmaxf(fmaxf(c00, c01), fmaxf(c10, c11));
        float p0 = __expf(c00 - m), p1 = __expf(c01 - m), p2 = __expf(c10 - m), p3 = __expf(c11 - m);
        float S = p0 + p1 + p2 + p3;
        float ox = 2.0f * (p0 * fxm[i00] + p1 * fxm[i01] + p2 * fxm[i10] + p3 * fxm[i11]) / S;
        float oy = 2.0f * (p0 * fym[i00] + p1 * fym[i01] + p2 * fym[i10] + p3 * fym[i11]) / S;
        int Y = (s1i * 16 + shq * 8 + fy + 4) & 511;
        int X = (s2i * 16 + swq * 8 + fx + 4) & 511;
        size_t base = (size_t)b * 2 * 512 * 512;
        f1[base + (size_t)Y * 512 + X] = ox;
        f1[base + (size_t)512 * 512 + (size_t)Y * 512 + X] = oy;
    }
}

// ---------------------------------------------------------------------------
// K5: bilinear resize (half-pixel, edge clamp) + scale, concat 4 outputs
// ---------------------------------------------------------------------------
__global__ __launch_bounds__(256) void resize_out(
    const float* __restrict__ f1e0, const float* __restrict__ f1e1,
    const float* __restrict__ f0e0, const float* __restrict__ f0e1,
    float* __restrict__ out)
{
    int idx = blockIdx.x * 256 + threadIdx.x;       // 0 .. 16777215
    int o = idx >> 22;
    int rem = idx & 4194303;
    int bc = rem >> 20;                              // b*2+ch
    int Y = (rem >> 10) & 1023;
    int X = rem & 1023;
    const float* src; int n; float invf, sc;
    if (o == 0)      { src = f1e1; n = 512; invf = 0.5f;  sc = 2.f; }
    else if (o == 1) { src = f1e0; n = 512; invf = 0.5f;  sc = 2.f; }
    else if (o == 2) { src = f0e0; n = 256; invf = 0.25f; sc = 4.f; }
    else             { src = f0e1; n = 256; invf = 0.25f; sc = 4.f; }
    float syf = ((float)Y + 0.5f) * invf - 0.5f;
    float sxf = ((float)X + 0.5f) * invf - 0.5f;
    int iy = (int)floorf(syf), ix = (int)floorf(sxf);
    float wy = syf - (float)iy, wx = sxf - (float)ix;
    int y0c = min(max(iy, 0), n - 1), y1c = min(max(iy + 1, 0), n - 1);
    int x0c = min(max(ix, 0), n - 1), x1c = min(max(ix + 1, 0), n - 1);
    const float* s = src + (size_t)bc * n * n;
    float v00 = s[(size_t)y0c * n + x0c], v01 = s[(size_t)y0c * n + x1c];
    float v10 = s[(size_t)y1c * n + x0c], v11 = s[(size_t)y1c * n + x1c];
    float v = (1.f - wy) * ((1.f - wx) * v00 + wx * v01) + wy * ((1.f - wx) * v10 + wx * v11);
    out[idx] = v * sc;
}

// ---------------------------------------------------------------------------
extern "C" void kernel_launch(void* const* d_in, const int* in_sizes, int n_in,
                              void* d_out, int out_size, void* d_ws, size_t ws_size,
                              hipStream_t stream)
{
    const float* feat0 = (const float*)d_in[0];
    const float* feat2 = (const float*)d_in[1];
    const float* wq = (const float*)d_in[2];
    const float* bq = (const float*)d_in[3];
    const float* wk = (const float*)d_in[4];
    const float* bk = (const float*)d_in[5];
    const float* btab = (const float*)d_in[6];

    char* w = (char*)d_ws;
    const size_t F = (size_t)16777216 * 2;   // bytes per bf16 NHWC field (2*256*256*128)
    __hip_bfloat16* q0 = (__hip_bfloat16*)(w);
    __hip_bfloat16* k0 = (__hip_bfloat16*)(w + F);
    __hip_bfloat16* q2 = (__hip_bfloat16*)(w + 2 * F);
    __hip_bfloat16* k2 = (__hip_bfloat16*)(w + 3 * F);
    __hip_bfloat16* in0T = (__hip_bfloat16*)(w + 4 * F);
    __hip_bfloat16* in1T = (__hip_bfloat16*)(w + 5 * F);
    __hip_bfloat16* w3q = (__hip_bfloat16*)(w + 6 * F);
    __hip_bfloat16* w3k = (__hip_bfloat16*)(w + 6 * F + 294912);
    float* f1e0 = (float*)(w + 6 * F + 2 * 294912);
    float* f1e1 = f1e0 + 1048576;   // 2*2*512*512
    float* f0e0 = f1e1 + 1048576;
    float* f0e1 = f0e0 + 262144;    // 2*2*256*256

    hipLaunchKernelGGL(transpose_nhwc, dim3(16384), dim3(256), 0, stream, feat0, in0T);
    hipLaunchKernelGGL(transpose_nhwc, dim3(16384), dim3(256), 0, stream, feat2, in1T);
    hipLaunchKernelGGL(prep_w, dim3(576), dim3(256), 0, stream, wq, wk, w3q, w3k);
    hipLaunchKernelGGL(conv3x3_mfma, dim3(2048, 4), dim3(256), 0, stream,
                       in0T, in1T, w3q, w3k, bq, bk, q0, k0, q2, k2);
    hipLaunchKernelGGL(window_flow, dim3(16384), dim3(256), 0, stream,
                       q0, k0, q2, k2, btab, f1e0, f1e1, f0e0, f0e1);
    hipLaunchKernelGGL(resize_out, dim3(65536), dim3(256), 0, stream,
                       f1e0, f1e1, f0e0, f0e1, (float*)d_out);
}

// Round 7
// 411.461 us; speedup vs baseline: 1.9317x; 1.0252x over previous
//
#include <hip/hip_runtime.h>
#include <hip/hip_bf16.h>
#include <math.h>

typedef __attribute__((ext_vector_type(8))) __bf16 bf16x8;
typedef __attribute__((ext_vector_type(4))) float f32x4;

#define HH 256
#define WW 256
#define SCALEF 0.08838834764831845f  // 128^-0.5

__device__ __forceinline__ void gload_lds16(const void* g, void* l) {
    __builtin_amdgcn_global_load_lds(
        (const __attribute__((address_space(1))) void*)g,
        (__attribute__((address_space(3))) void*)l, 16, 0, 0);
}

// ---------------------------------------------------------------------------
// K1: NCHW f32 -> NHWC bf16 transpose
// ---------------------------------------------------------------------------
__global__ __launch_bounds__(256) void transpose_nhwc(const float* __restrict__ in,
                                                      __hip_bfloat16* __restrict__ out)
{
    int blk = blockIdx.x;
    int c0 = (blk & 3) * 32;
    int x0 = ((blk >> 2) & 7) * 32;
    int by = blk >> 5;              // b*256 + y
    int y = by & 255, b = by >> 8;
    __shared__ float tile[32][33];
    int tx = threadIdx.x & 31, ty = threadIdx.x >> 5;   // ty 0..7
#pragma unroll
    for (int i = 0; i < 4; i++) {
        int c = c0 + ty + 8 * i;
        tile[ty + 8 * i][tx] = in[(((size_t)b * 128 + c) * HH + y) * WW + x0 + tx];
    }
    __syncthreads();
#pragma unroll
    for (int i = 0; i < 4; i++) {
        int x = x0 + ty + 8 * i;
        out[(((size_t)b * HH + y) * WW + x) * 128 + c0 + tx] =
            __float2bfloat16(tile[tx][ty + 8 * i]);
    }
}

// ---------------------------------------------------------------------------
// K2: weight repack -> chunk-major, swizzled for global_load_lds staging.
// src (co,ci,ky,kx). k_global = tap*128+ci. chunk q = k_global>>5 (32-k chunks).
// dst elem = q*4096 + co*32 + ((kin>>3) ^ ((co>>1)&3))*8 + (kin&7), kin=k_global&31
// ---------------------------------------------------------------------------
__global__ __launch_bounds__(256) void prep_w(const float* __restrict__ wq,
                                              const float* __restrict__ wk,
                                              __hip_bfloat16* __restrict__ w3q,
                                              __hip_bfloat16* __restrict__ w3k)
{
    int i = blockIdx.x * 256 + threadIdx.x;
    if (i >= 128 * 128 * 9) return;
    int co = i / (128 * 9);
    int r = i - co * 128 * 9;
    int ci = r / 9;
    int tap = r - ci * 9;
    int kg = tap * 128 + ci;
    int q = kg >> 5, kin = kg & 31;
    int slot = (kin >> 3) ^ ((co >> 1) & 3);
    int dst = q * 4096 + co * 32 + slot * 8 + (kin & 7);
    w3q[dst] = __float2bfloat16(wq[i]);
    w3k[dst] = __float2bfloat16(wk[i]);
}

// ---------------------------------------------------------------------------
// K3: conv3x3 (SAME) implicit GEMM, q+k MERGED (shared input patch).
// Block: 8x8 px, both mats, 128 co. 4 waves; wave w: co [32w,32w+32) x {q,k}.
// A: halo patch in LDS (swizzled) -- each A fragment feeds 4 MFMAs.
// B: 32-k chunks of BOTH mats triple-buffered via global_load_lds, dist 2,
//    counted vmcnt(4) + raw s_barrier (never drain mid-loop).
// Out: staged in LDS (aliases patch) -> coalesced uint4 stores, q then k.
// ---------------------------------------------------------------------------
__global__ __launch_bounds__(256, 2) void conv3x3_mfma(
    const __hip_bfloat16* __restrict__ in0, const __hip_bfloat16* __restrict__ in1,
    const __hip_bfloat16* __restrict__ w3q, const __hip_bfloat16* __restrict__ w3k,
    const float* __restrict__ bq, const float* __restrict__ bk,
    __hip_bfloat16* __restrict__ q0, __hip_bfloat16* __restrict__ k0,
    __hip_bfloat16* __restrict__ q2, __hip_bfloat16* __restrict__ k2)
{
    const int half = blockIdx.y;          // 0: in0 -> (q0,k0), 1: in1 -> (q2,k2)
    const __hip_bfloat16* src = half ? in1 : in0;
    __hip_bfloat16* qdst = half ? q2 : q0;
    __hip_bfloat16* kdst = half ? k2 : k0;

    const int blk = blockIdx.x;           // 0..2047
    const int b = blk >> 10;
    const int rr = blk & 1023;
    const int y0 = (rr >> 5) << 3;
    const int x0 = (rr & 31) << 3;

    __shared__ __align__(16) char smem[25600 + 3 * 16384];  // patch + B 3x(2x8KB)
    char* patch = smem;
    char* ldsB = smem + 25600;

    const int tid = threadIdx.x;

    // ---- stage input halo patch (swizzled 16B slots) ----
    for (int idx = tid; idx < 1600; idx += 256) {
        int p = idx >> 4, lc = idx & 15;
        int py = p / 10, px = p - py * 10;
        int gy = y0 + py - 1, gx = x0 + px - 1;
        uint4 v = make_uint4(0u, 0u, 0u, 0u);
        if (gy >= 0 && gy < HH && gx >= 0 && gx < WW)
            v = *(const uint4*)(src + ((((size_t)b * HH + gy) * WW + gx) << 7) + lc * 8);
        *(uint4*)(patch + p * 256 + ((lc ^ (p & 7)) << 4)) = v;
    }
    // ---- async-stage chunks 0,1 of both mats into buf 0,1 ----
    {
        const char* sq = (const char*)w3q + tid * 16;
        const char* sk = (const char*)w3k + tid * 16;
#pragma unroll
        for (int c = 0; c < 2; ++c) {
            char* dl = ldsB + c * 16384 + tid * 16;
            gload_lds16(sq + c * 8192, dl);
            gload_lds16(sq + c * 8192 + 4096, dl + 4096);
            gload_lds16(sk + c * 8192, dl + 8192);
            gload_lds16(sk + c * 8192 + 4096, dl + 12288);
        }
    }
    __syncthreads();   // full drain once (patch + chunks 0,1 ready)

    const int lane = tid & 63;
    const int wv = tid >> 6;
    const int l15 = lane & 15;
    const int kq = lane >> 4;
    const int myb = l15 >> 3, mxb = l15 & 7;
    const int c0 = wv * 32 + l15;
    const int c1 = c0 + 16;
    const int bswz = ((kq ^ ((l15 >> 1) & 3)) << 4);
    const int bO0 = c0 * 64 + bswz;
    const int bO1 = c1 * 64 + bswz;

    f32x4 accq[4][2], acck[4][2];
#pragma unroll
    for (int mi = 0; mi < 4; mi++)
#pragma unroll
        for (int n = 0; n < 2; n++) {
            accq[mi][n] = (f32x4){0.f, 0.f, 0.f, 0.f};
            acck[mi][n] = (f32x4){0.f, 0.f, 0.f, 0.f};
        }

#pragma unroll
    for (int q = 0; q < 36; ++q) {
        const int t = q >> 2, cc = q & 3;
        const int ky = t / 3, kx = t - ky * 3;
        if (q + 2 < 36) {                 // prefetch distance 2 -> buf[(q+2)%3]
            const char* sq = (const char*)w3q + (size_t)(q + 2) * 8192 + tid * 16;
            const char* sk = (const char*)w3k + (size_t)(q + 2) * 8192 + tid * 16;
            char* dl = ldsB + ((q + 2) % 3) * 16384 + tid * 16;
            gload_lds16(sq, dl);
            gload_lds16(sq + 4096, dl + 4096);
            gload_lds16(sk, dl + 8192);
            gload_lds16(sk + 4096, dl + 12288);
        }
        const char* bb = ldsB + (q % 3) * 16384;
        bf16x8 q0f = *(const bf16x8*)(bb + bO0);
        bf16x8 q1f = *(const bf16x8*)(bb + bO1);
        bf16x8 k0f = *(const bf16x8*)(bb + 8192 + bO0);
        bf16x8 k1f = *(const bf16x8*)(bb + 8192 + bO1);
        const int slot = cc * 4 + kq;
#pragma unroll
        for (int mi = 0; mi < 4; ++mi) {
            int pos = (mi * 2 + myb + ky) * 10 + (mxb + kx);
            bf16x8 a = *(const bf16x8*)(patch + pos * 256 + ((slot ^ (pos & 7)) << 4));
            accq[mi][0] = __builtin_amdgcn_mfma_f32_16x16x32_bf16(a, q0f, accq[mi][0], 0, 0, 0);
            accq[mi][1] = __builtin_amdgcn_mfma_f32_16x16x32_bf16(a, q1f, accq[mi][1], 0, 0, 0);
            acck[mi][0] = __builtin_amdgcn_mfma_f32_16x16x32_bf16(a, k0f, acck[mi][0], 0, 0, 0);
            acck[mi][1] = __builtin_amdgcn_mfma_f32_16x16x32_bf16(a, k1f, acck[mi][1], 0, 0, 0);
        }
        if (q + 1 < 36) {
            // chunk q+1's 4 DMA ops must land; q+2's 4 stay in flight
            if (q + 2 < 36) asm volatile("s_waitcnt vmcnt(4)" ::: "memory");
            else            asm volatile("s_waitcnt vmcnt(0)" ::: "memory");
            __builtin_amdgcn_s_barrier();
            __builtin_amdgcn_sched_barrier(0);
        }
    }
    __syncthreads();   // all patch/B reads done before stage overwrite

    // ---- epilogue: bias, stage in LDS (aliases patch), coalesced store ----
    float bvq0 = bq[c0], bvq1 = bq[c1];
    float bvk0 = bk[c0], bvk1 = bk[c1];
    __hip_bfloat16* stage = (__hip_bfloat16*)patch;   // [64 px][stride 136 el]
#pragma unroll
    for (int mi = 0; mi < 4; ++mi) {
#pragma unroll
        for (int r = 0; r < 4; ++r) {
            int m = mi * 16 + kq * 4 + r;
            stage[m * 136 + c0] = __float2bfloat16(accq[mi][0][r] + bvq0);
            stage[m * 136 + c1] = __float2bfloat16(accq[mi][1][r] + bvq1);
        }
    }
    __syncthreads();
#pragma unroll
    for (int it = 0; it < 4; ++it) {
        int idx = it * 256 + tid;
        int p = idx >> 4, lc = idx & 15;
        int y = y0 + (p >> 3), x = x0 + (p & 7);
        uint4 v = *(const uint4*)((const char*)patch + p * 272 + lc * 16);
        *(uint4*)(qdst + ((((size_t)b * HH + y) * WW + x) << 7) + lc * 8) = v;
    }
    __syncthreads();   // q-stage reads done before k-stage overwrite
#pragma unroll
    for (int mi = 0; mi < 4; ++mi) {
#pragma unroll
        for (int r = 0; r < 4; ++r) {
            int m = mi * 16 + kq * 4 + r;
            stage[m * 136 + c0] = __float2bfloat16(acck[mi][0][r] + bvk0);
            stage[m * 136 + c1] = __float2bfloat16(acck[mi][1][r] + bvk1);
        }
    }
    __syncthreads();
#pragma unroll
    for (int it = 0; it < 4; ++it) {
        int idx = it * 256 + tid;
        int p = idx >> 4, lc = idx & 15;
        int y = y0 + (p >> 3), x = x0 + (p & 7);
        uint4 v = *(const uint4*)((const char*)patch + p * 272 + lc * 16);
        *(uint4*)(kdst + ((((size_t)b * HH + y) * WW + x) << 7) + lc * 8) = v;
    }
}

// ---------------------------------------------------------------------------
// K4: per-(window, estimate x shift) correlation + flow_bsd + flow_mid.
// cls aliases qt/kt (dead after MFMA) -> 36.7 KB LDS -> 4 blocks/CU.
// Grid flattened 16384; decode keeps a window's 8 combos on one XCD,
// temporally adjacent (L2 reuse of the window's q/k data).
// ---------------------------------------------------------------------------
#define WPAD 136     // 272B rows: 2-way banks (free)
#define CST 66       // cls row stride (floats)
__global__ __launch_bounds__(256, 4) void window_flow(
    const __hip_bfloat16* __restrict__ q0, const __hip_bfloat16* __restrict__ k0,
    const __hip_bfloat16* __restrict__ q2, const __hip_bfloat16* __restrict__ k2,
    const float* __restrict__ btab,
    float* __restrict__ f1e0, float* __restrict__ f1e1,
    float* __restrict__ f0e0, float* __restrict__ f0e1)
{
    const int id = blockIdx.x;               // 0..16383
    const int xcd = id & 7;
    const int slot = id >> 3;
    const int combo = slot & 7;               // 8 combos adjacent on one XCD
    const int wdx = (slot >> 3) * 8 + xcd;    // 0..2047

    const int e = combo >> 2;
    const int sflag = combo & 3;
    const int shq = (sflag >> 1) & 1;        // shift_h flag == quadrant y
    const int swq = sflag & 1;               // shift_w flag == quadrant x
    const int sh = shq ? 4 : 0, sw = swq ? 4 : 0;
    const __hip_bfloat16* qf = e ? q2 : q0;
    const __hip_bfloat16* kf = e ? k0 : k2;
    float* f1 = e ? f1e1 : f1e0;
    float* f0 = e ? f0e1 : f0e0;

    const int b = wdx >> 10;
    const int s1i = (wdx >> 5) & 31;
    const int s2i = wdx & 31;

    __shared__ __align__(16) char wsm[64 * WPAD * 2 * 2];   // 34816 B
    __hip_bfloat16* qt = (__hip_bfloat16*)wsm;
    __hip_bfloat16* kt = (__hip_bfloat16*)(wsm + 64 * WPAD * 2);
    float* cls = (float*)wsm;                 // aliases qt/kt after MFMA phase
    __shared__ float cmid[81], fxm[81], fym[81];
    __shared__ float sb[225];

    const int tid = threadIdx.x;
    if (tid < 225) sb[tid] = btab[tid];

    for (int idx = tid; idx < 2048; idx += 256) {
        int which = idx >> 10;
        int p = (idx >> 4) & 63, lc = idx & 15;
        int iy = p >> 3, ix = p & 7;
        int gy = (s1i * 8 + iy + sh) & 255;
        int gx = (s2i * 8 + ix + sw) & 255;
        const __hip_bfloat16* srcf = which ? kf : qf;
        uint4 v = *(const uint4*)(srcf + ((((size_t)b * HH + gy) * WW + gx) << 7) + lc * 8);
        __hip_bfloat16* dstt = which ? kt : qt;
        *(uint4*)(dstt + p * WPAD + lc * 8) = v;
    }
    __syncthreads();

    // corr = qw . kw^T   (M=64, N=64, K=128), 4 waves over M
    const int lane = tid & 63;
    const int wv = tid >> 6;
    const int l15 = lane & 15;
    const int kq = lane >> 4;

    f32x4 acc[4];
#pragma unroll
    for (int nf = 0; nf < 4; nf++) acc[nf] = (f32x4){0.f, 0.f, 0.f, 0.f};

#pragma unroll
    for (int kc = 0; kc < 4; ++kc) {
        bf16x8 a = *(const bf16x8*)(qt + (wv * 16 + l15) * WPAD + kc * 32 + kq * 8);
#pragma unroll
        for (int nf = 0; nf < 4; ++nf) {
            bf16x8 bb = *(const bf16x8*)(kt + (nf * 16 + l15) * WPAD + kc * 32 + kq * 8);
            acc[nf] = __builtin_amdgcn_mfma_f32_16x16x32_bf16(a, bb, acc[nf], 0, 0, 0);
        }
    }
    __syncthreads();   // qt/kt reads complete before cls overwrites them

    // epilogue: scale + relative-pos bias + shift mask -> cls
#pragma unroll
    for (int nf = 0; nf < 4; ++nf) {
#pragma unroll
        for (int r = 0; r < 4; ++r) {
            int row = wv * 16 + kq * 4 + r;
            int col = nf * 16 + l15;
            int qy = row >> 3, qx = row & 7;
            int ty = col >> 3, tx = col & 7;
            float v = acc[nf][r] * SCALEF + sb[(qy - ty + 7) * 15 + (qx - tx + 7)];
            if (sflag) {
                int rhq = 0, rwq = 0, rht = 0, rwt = 0;
                if (shq && s1i == 31) { rhq = (qy < 4) ? 1 : 2; rht = (ty < 4) ? 1 : 2; }
                if (swq && s2i == 31) { rwq = (qx < 4) ? 1 : 2; rwt = (tx < 4) ? 1 : 2; }
                int regq, regt;
                if (shq && swq) { regq = rhq * 3 + rwq; regt = rht * 3 + rwt; }
                else if (shq)   { regq = rhq; regt = rht; }
                else            { regq = rwq; regt = rwt; }
                if (regq != regt) v -= 10000.0f;
            }
            cls[row * CST + col] = v;
        }
    }
    __syncthreads();

    const int rg = tid >> 4;       // 16 row-groups
    const int lg = tid & 15;       // 16 lanes per row

    // ---- flow_bsd: 16 rows, one 16-lane group each, 4 consecutive cols/lane ----
    {
        int fy = rg >> 2, fx = rg & 3;
        int qy = fy + 2, qx = fx + 2;
        const float* rowp = &cls[(qy * 8 + qx) * CST];
        float v[4];
        float mx = -1e30f;
#pragma unroll
        for (int j = 0; j < 4; ++j) { v[j] = rowp[lg * 4 + j]; mx = fmaxf(mx, v[j]); }
#pragma unroll
        for (int m = 8; m >= 1; m >>= 1) mx = fmaxf(mx, __shfl_xor(mx, m));
        float S = 0.f, sx = 0.f, sy = 0.f;
#pragma unroll
        for (int j = 0; j < 4; ++j) {
            int t = lg * 4 + j;
            float p = __expf(v[j] - mx);
            S += p; sx += p * (float)(t & 7); sy += p * (float)(t >> 3);
        }
#pragma unroll
        for (int m = 8; m >= 1; m >>= 1) {
            S += __shfl_xor(S, m); sx += __shfl_xor(sx, m); sy += __shfl_xor(sy, m);
        }
        if (lg == 0) {
            float fxv = sx / S - (float)qx;
            float fyv = sy / S - (float)qy;
            int Y = (s1i * 8 + shq * 4 + fy + 2) & 255;
            int X = (s2i * 8 + swq * 4 + fx + 2) & 255;
            size_t base = (size_t)b * 2 * HH * WW;
            f0[base + (size_t)Y * WW + X] = fxv;
            f0[base + (size_t)HH * WW + (size_t)Y * WW + X] = fyv;
        }
    }

    // ---- flow_mid row softmaxes: 81 rows, 16 at a time ----
    for (int it = 0; it < 6; ++it) {
        int rm = it * 16 + rg;
        if (rm < 81) {
            int a = rm / 9, bc = rm - a * 9;
            float v[4];
            float mx = -1e30f;
#pragma unroll
            for (int j = 0; j < 4; ++j) {
                int t = lg + 16 * j;
                int h2 = t >> 3, w2 = t & 7;
                int qy = a + 3 - h2, qx = bc + 3 - w2;
                v[j] = ((unsigned)qy < 8u && (unsigned)qx < 8u) ? cls[(qy * 8 + qx) * CST + t] : 0.0f;
                mx = fmaxf(mx, v[j]);
            }
#pragma unroll
            for (int m = 8; m >= 1; m >>= 1) mx = fmaxf(mx, __shfl_xor(mx, m));
            float S = 0.f, sc = 0.f, sx = 0.f, sy = 0.f;
#pragma unroll
            for (int j = 0; j < 4; ++j) {
                int t = lg + 16 * j;
                float p = __expf(v[j] - mx);
                S += p; sc += v[j] * p; sx += p * (float)(t & 7); sy += p * (float)(t >> 3);
            }
#pragma unroll
            for (int m = 8; m >= 1; m >>= 1) {
                S += __shfl_xor(S, m); sc += __shfl_xor(sc, m);
                sx += __shfl_xor(sx, m); sy += __shfl_xor(sy, m);
            }
            if (lg == 0) {
                float inv = 1.0f / S;
                cmid[rm] = sc * inv;
                fxm[rm] = sx * inv - (float)(bc + 3) * 0.5f;
                fym[rm] = sy * inv - (float)(a + 3) * 0.5f;
            }
        }
    }
    __syncthreads();

    // flow_mid quadrant combine -> 8x8
    if (tid < 64) {
        int fy = tid >> 3, fx = tid & 7;
        int i00 = fy * 9 + fx, i01 = i00 + 1, i10 = i00 + 9, i11 = i00 + 10;
        float c00 = cmid[i00], c01 = cmid[i01], c10 = cmid[i10], c11 = cmid[i11];
        float m = fmaxf(fmaxf(c00, c01), fmaxf(c10, c11));
        float p0 = __expf(c00 - m), p1 = __expf(c01 - m), p2 = __expf(c10 - m), p3 = __expf(c11 - m);
        float S = p0 + p1 + p2 + p3;
        float ox = 2.0f * (p0 * fxm[i00] + p1 * fxm[i01] + p2 * fxm[i10] + p3 * fxm[i11]) / S;
        float oy = 2.0f * (p0 * fym[i00] + p1 * fym[i01] + p2 * fym[i10] + p3 * fym[i11]) / S;
        int Y = (s1i * 16 + shq * 8 + fy + 4) & 511;
        int X = (s2i * 16 + swq * 8 + fx + 4) & 511;
        size_t base = (size_t)b * 2 * 512 * 512;
        f1[base + (size_t)Y * 512 + X] = ox;
        f1[base + (size_t)512 * 512 + (size_t)Y * 512 + X] = oy;
    }
}

// ---------------------------------------------------------------------------
// K5: bilinear resize (half-pixel, edge clamp) + scale, concat 4 outputs
// ---------------------------------------------------------------------------
__global__ __launch_bounds__(256) void resize_out(
    const float* __restrict__ f1e0, const float* __restrict__ f1e1,
    const float* __restrict__ f0e0, const float* __restrict__ f0e1,
    float* __restrict__ out)
{
    int idx = blockIdx.x * 256 + threadIdx.x;       // 0 .. 16777215
    int o = idx >> 22;
    int rem = idx & 4194303;
    int bc = rem >> 20;                              // b*2+ch
    int Y = (rem >> 10) & 1023;
    int X = rem & 1023;
    const float* src; int n; float invf, sc;
    if (o == 0)      { src = f1e1; n = 512; invf = 0.5f;  sc = 2.f; }
    else if (o == 1) { src = f1e0; n = 512; invf = 0.5f;  sc = 2.f; }
    else if (o == 2) { src = f0e0; n = 256; invf = 0.25f; sc = 4.f; }
    else             { src = f0e1; n = 256; invf = 0.25f; sc = 4.f; }
    float syf = ((float)Y + 0.5f) * invf - 0.5f;
    float sxf = ((float)X + 0.5f) * invf - 0.5f;
    int iy = (int)floorf(syf), ix = (int)floorf(sxf);
    float wy = syf - (float)iy, wx = sxf - (float)ix;
    int y0c = min(max(iy, 0), n - 1), y1c = min(max(iy + 1, 0), n - 1);
    int x0c = min(max(ix, 0), n - 1), x1c = min(max(ix + 1, 0), n - 1);
    const float* s = src + (size_t)bc * n * n;
    float v00 = s[(size_t)y0c * n + x0c], v01 = s[(size_t)y0c * n + x1c];
    float v10 = s[(size_t)y1c * n + x0c], v11 = s[(size_t)y1c * n + x1c];
    float v = (1.f - wy) * ((1.f - wx) * v00 + wx * v01) + wy * ((1.f - wx) * v10 + wx * v11);
    out[idx] = v * sc;
}

// ---------------------------------------------------------------------------
extern "C" void kernel_launch(void* const* d_in, const int* in_sizes, int n_in,
                              void* d_out, int out_size, void* d_ws, size_t ws_size,
                              hipStream_t stream)
{
    const float* feat0 = (const float*)d_in[0];
    const float* feat2 = (const float*)d_in[1];
    const float* wq = (const float*)d_in[2];
    const float* bq = (const float*)d_in[3];
    const float* wk = (const float*)d_in[4];
    const float* bk = (const float*)d_in[5];
    const float* btab = (const float*)d_in[6];

    char* w = (char*)d_ws;
    const size_t F = (size_t)16777216 * 2;   // bytes per bf16 NHWC field (2*256*256*128)
    __hip_bfloat16* q0 = (__hip_bfloat16*)(w);
    __hip_bfloat16* k0 = (__hip_bfloat16*)(w + F);
    __hip_bfloat16* q2 = (__hip_bfloat16*)(w + 2 * F);
    __hip_bfloat16* k2 = (__hip_bfloat16*)(w + 3 * F);
    __hip_bfloat16* in0T = (__hip_bfloat16*)(w + 4 * F);
    __hip_bfloat16* in1T = (__hip_bfloat16*)(w + 5 * F);
    __hip_bfloat16* w3q = (__hip_bfloat16*)(w + 6 * F);
    __hip_bfloat16* w3k = (__hip_bfloat16*)(w + 6 * F + 294912);
    float* f1e0 = (float*)(w + 6 * F + 2 * 294912);
    float* f1e1 = f1e0 + 1048576;   // 2*2*512*512
    float* f0e0 = f1e1 + 1048576;
    float* f0e1 = f0e0 + 262144;    // 2*2*256*256

    hipLaunchKernelGGL(transpose_nhwc, dim3(16384), dim3(256), 0, stream, feat0, in0T);
    hipLaunchKernelGGL(transpose_nhwc, dim3(16384), dim3(256), 0, stream, feat2, in1T);
    hipLaunchKernelGGL(prep_w, dim3(576), dim3(256), 0, stream, wq, wk, w3q, w3k);
    hipLaunchKernelGGL(conv3x3_mfma, dim3(2048, 2), dim3(256), 0, stream,
                       in0T, in1T, w3q, w3k, bq, bk, q0, k0, q2, k2);
    hipLaunchKernelGGL(window_flow, dim3(16384), dim3(256), 0, stream,
                       q0, k0, q2, k2, btab, f1e0, f1e1, f0e0, f0e1);
    hipLaunchKernelGGL(resize_out, dim3(65536), dim3(256), 0, stream,
                       f1e0, f1e1, f0e0, f0e1, (float*)d_out);
}

// Round 9
// 376.007 us; speedup vs baseline: 2.1138x; 1.0943x over previous
//
#include <hip/hip_runtime.h>
#include <hip/hip_bf16.h>
#include <math.h>

typedef __attribute__((ext_vector_type(8))) __bf16 bf16x8;
typedef __attribute__((ext_vector_type(4))) float f32x4;

#define HH 256
#define WW 256
#define SCALEF 0.08838834764831845f  // 128^-0.5

__device__ __forceinline__ void gload_lds16(const void* g, void* l) {
    __builtin_amdgcn_global_load_lds(
        (const __attribute__((address_space(1))) void*)g,
        (__attribute__((address_space(3))) void*)l, 16, 0, 0);
}

// ---------------------------------------------------------------------------
// K1: NCHW f32 -> NHWC bf16 transpose
// ---------------------------------------------------------------------------
__global__ __launch_bounds__(256) void transpose_nhwc(const float* __restrict__ in,
                                                      __hip_bfloat16* __restrict__ out)
{
    int blk = blockIdx.x;
    int c0 = (blk & 3) * 32;
    int x0 = ((blk >> 2) & 7) * 32;
    int by = blk >> 5;              // b*256 + y
    int y = by & 255, b = by >> 8;
    __shared__ float tile[32][33];
    int tx = threadIdx.x & 31, ty = threadIdx.x >> 5;   // ty 0..7
#pragma unroll
    for (int i = 0; i < 4; i++) {
        int c = c0 + ty + 8 * i;
        tile[ty + 8 * i][tx] = in[(((size_t)b * 128 + c) * HH + y) * WW + x0 + tx];
    }
    __syncthreads();
#pragma unroll
    for (int i = 0; i < 4; i++) {
        int x = x0 + ty + 8 * i;
        out[(((size_t)b * HH + y) * WW + x) * 128 + c0 + tx] =
            __float2bfloat16(tile[tx][ty + 8 * i]);
    }
}

// ---------------------------------------------------------------------------
// K2: weight repack -> chunk-major, swizzled for global_load_lds staging.
// ---------------------------------------------------------------------------
__global__ __launch_bounds__(256) void prep_w(const float* __restrict__ wq,
                                              const float* __restrict__ wk,
                                              __hip_bfloat16* __restrict__ w3q,
                                              __hip_bfloat16* __restrict__ w3k)
{
    int i = blockIdx.x * 256 + threadIdx.x;
    if (i >= 128 * 128 * 9) return;
    int co = i / (128 * 9);
    int r = i - co * 128 * 9;
    int ci = r / 9;
    int tap = r - ci * 9;
    int kg = tap * 128 + ci;
    int q = kg >> 5, kin = kg & 31;
    int slot = (kin >> 3) ^ ((co >> 1) & 3);
    int dst = q * 4096 + co * 32 + slot * 8 + (kin & 7);
    w3q[dst] = __float2bfloat16(wq[i]);
    w3k[dst] = __float2bfloat16(wk[i]);
}

// ---------------------------------------------------------------------------
// K3: conv3x3 (SAME) implicit GEMM, q+k MERGED (shared input patch).
// ---------------------------------------------------------------------------
__global__ __launch_bounds__(256, 2) void conv3x3_mfma(
    const __hip_bfloat16* __restrict__ in0, const __hip_bfloat16* __restrict__ in1,
    const __hip_bfloat16* __restrict__ w3q, const __hip_bfloat16* __restrict__ w3k,
    const float* __restrict__ bq, const float* __restrict__ bk,
    __hip_bfloat16* __restrict__ q0, __hip_bfloat16* __restrict__ k0,
    __hip_bfloat16* __restrict__ q2, __hip_bfloat16* __restrict__ k2)
{
    const int half = blockIdx.y;          // 0: in0 -> (q0,k0), 1: in1 -> (q2,k2)
    const __hip_bfloat16* src = half ? in1 : in0;
    __hip_bfloat16* qdst = half ? q2 : q0;
    __hip_bfloat16* kdst = half ? k2 : k0;

    const int blk = blockIdx.x;           // 0..2047
    const int b = blk >> 10;
    const int rr = blk & 1023;
    const int y0 = (rr >> 5) << 3;
    const int x0 = (rr & 31) << 3;

    __shared__ __align__(16) char smem[25600 + 3 * 16384];  // patch + B 3x(2x8KB)
    char* patch = smem;
    char* ldsB = smem + 25600;

    const int tid = threadIdx.x;

    // ---- stage input halo patch (swizzled 16B slots) ----
    for (int idx = tid; idx < 1600; idx += 256) {
        int p = idx >> 4, lc = idx & 15;
        int py = p / 10, px = p - py * 10;
        int gy = y0 + py - 1, gx = x0 + px - 1;
        uint4 v = make_uint4(0u, 0u, 0u, 0u);
        if (gy >= 0 && gy < HH && gx >= 0 && gx < WW)
            v = *(const uint4*)(src + ((((size_t)b * HH + gy) * WW + gx) << 7) + lc * 8);
        *(uint4*)(patch + p * 256 + ((lc ^ (p & 7)) << 4)) = v;
    }
    // ---- async-stage chunks 0,1 of both mats into buf 0,1 ----
    {
        const char* sq = (const char*)w3q + tid * 16;
        const char* sk = (const char*)w3k + tid * 16;
#pragma unroll
        for (int c = 0; c < 2; ++c) {
            char* dl = ldsB + c * 16384 + tid * 16;
            gload_lds16(sq + c * 8192, dl);
            gload_lds16(sq + c * 8192 + 4096, dl + 4096);
            gload_lds16(sk + c * 8192, dl + 8192);
            gload_lds16(sk + c * 8192 + 4096, dl + 12288);
        }
    }
    __syncthreads();   // full drain once (patch + chunks 0,1 ready)

    const int lane = tid & 63;
    const int wv = tid >> 6;
    const int l15 = lane & 15;
    const int kq = lane >> 4;
    const int myb = l15 >> 3, mxb = l15 & 7;
    const int c0 = wv * 32 + l15;
    const int c1 = c0 + 16;
    const int bswz = ((kq ^ ((l15 >> 1) & 3)) << 4);
    const int bO0 = c0 * 64 + bswz;
    const int bO1 = c1 * 64 + bswz;

    f32x4 accq[4][2], acck[4][2];
#pragma unroll
    for (int mi = 0; mi < 4; mi++)
#pragma unroll
        for (int n = 0; n < 2; n++) {
            accq[mi][n] = (f32x4){0.f, 0.f, 0.f, 0.f};
            acck[mi][n] = (f32x4){0.f, 0.f, 0.f, 0.f};
        }

#pragma unroll
    for (int q = 0; q < 36; ++q) {
        const int t = q >> 2, cc = q & 3;
        const int ky = t / 3, kx = t - ky * 3;
        if (q + 2 < 36) {                 // prefetch distance 2 -> buf[(q+2)%3]
            const char* sq = (const char*)w3q + (size_t)(q + 2) * 8192 + tid * 16;
            const char* sk = (const char*)w3k + (size_t)(q + 2) * 8192 + tid * 16;
            char* dl = ldsB + ((q + 2) % 3) * 16384 + tid * 16;
            gload_lds16(sq, dl);
            gload_lds16(sq + 4096, dl + 4096);
            gload_lds16(sk, dl + 8192);
            gload_lds16(sk + 4096, dl + 12288);
        }
        const char* bb = ldsB + (q % 3) * 16384;
        bf16x8 q0f = *(const bf16x8*)(bb + bO0);
        bf16x8 q1f = *(const bf16x8*)(bb + bO1);
        bf16x8 k0f = *(const bf16x8*)(bb + 8192 + bO0);
        bf16x8 k1f = *(const bf16x8*)(bb + 8192 + bO1);
        const int slot = cc * 4 + kq;
#pragma unroll
        for (int mi = 0; mi < 4; ++mi) {
            int pos = (mi * 2 + myb + ky) * 10 + (mxb + kx);
            bf16x8 a = *(const bf16x8*)(patch + pos * 256 + ((slot ^ (pos & 7)) << 4));
            accq[mi][0] = __builtin_amdgcn_mfma_f32_16x16x32_bf16(a, q0f, accq[mi][0], 0, 0, 0);
            accq[mi][1] = __builtin_amdgcn_mfma_f32_16x16x32_bf16(a, q1f, accq[mi][1], 0, 0, 0);
            acck[mi][0] = __builtin_amdgcn_mfma_f32_16x16x32_bf16(a, k0f, acck[mi][0], 0, 0, 0);
            acck[mi][1] = __builtin_amdgcn_mfma_f32_16x16x32_bf16(a, k1f, acck[mi][1], 0, 0, 0);
        }
        if (q + 1 < 36) {
            if (q + 2 < 36) asm volatile("s_waitcnt vmcnt(4)" ::: "memory");
            else            asm volatile("s_waitcnt vmcnt(0)" ::: "memory");
            __builtin_amdgcn_s_barrier();
            __builtin_amdgcn_sched_barrier(0);
        }
    }
    __syncthreads();

    // ---- epilogue: bias, stage in LDS (aliases patch), coalesced store ----
    float bvq0 = bq[c0], bvq1 = bq[c1];
    float bvk0 = bk[c0], bvk1 = bk[c1];
    __hip_bfloat16* stage = (__hip_bfloat16*)patch;   // [64 px][stride 136 el]
#pragma unroll
    for (int mi = 0; mi < 4; ++mi) {
#pragma unroll
        for (int r = 0; r < 4; ++r) {
            int m = mi * 16 + kq * 4 + r;
            stage[m * 136 + c0] = __float2bfloat16(accq[mi][0][r] + bvq0);
            stage[m * 136 + c1] = __float2bfloat16(accq[mi][1][r] + bvq1);
        }
    }
    __syncthreads();
#pragma unroll
    for (int it = 0; it < 4; ++it) {
        int idx = it * 256 + tid;
        int p = idx >> 4, lc = idx & 15;
        int y = y0 + (p >> 3), x = x0 + (p & 7);
        uint4 v = *(const uint4*)((const char*)patch + p * 272 + lc * 16);
        *(uint4*)(qdst + ((((size_t)b * HH + y) * WW + x) << 7) + lc * 8) = v;
    }
    __syncthreads();
#pragma unroll
    for (int mi = 0; mi < 4; ++mi) {
#pragma unroll
        for (int r = 0; r < 4; ++r) {
            int m = mi * 16 + kq * 4 + r;
            stage[m * 136 + c0] = __float2bfloat16(acck[mi][0][r] + bvk0);
            stage[m * 136 + c1] = __float2bfloat16(acck[mi][1][r] + bvk1);
        }
    }
    __syncthreads();
#pragma unroll
    for (int it = 0; it < 4; ++it) {
        int idx = it * 256 + tid;
        int p = idx >> 4, lc = idx & 15;
        int y = y0 + (p >> 3), x = x0 + (p & 7);
        uint4 v = *(const uint4*)((const char*)patch + p * 272 + lc * 16);
        *(uint4*)(kdst + ((((size_t)b * HH + y) * WW + x) << 7) + lc * 8) = v;
    }
}

// ---------------------------------------------------------------------------
// K4: per-(window, estimate x shift) correlation + flow_bsd + flow_mid.
// qt/kt: linear 256B rows staged via global_load_lds with XOR-preswizzled
// source; reads apply the same XOR (both-sides involution).
// Softmax: NO max-subtract. Mask constant is -40 (not -10000): masked weight
// e^-40 is < fp32 sum precision relative to unmasked (~±5), and FULLY-masked
// rows (boundary windows, e.g. a=4,bc=4) get a UNIFORM -40 shift -> softmax
// shift-invariance reproduces the reference exactly with S ~ 64*e^-40 (normal
// fp32, no 0/0 NaN -- the round-8 failure).
// ---------------------------------------------------------------------------
#define CST 66       // cls row stride (floats)
__global__ __launch_bounds__(256, 4) void window_flow(
    const __hip_bfloat16* __restrict__ q0, const __hip_bfloat16* __restrict__ k0,
    const __hip_bfloat16* __restrict__ q2, const __hip_bfloat16* __restrict__ k2,
    const float* __restrict__ btab,
    float* __restrict__ f1e0, float* __restrict__ f1e1,
    float* __restrict__ f0e0, float* __restrict__ f0e1)
{
    const int id = blockIdx.x;               // 0..16383
    const int xcd = id & 7;
    const int slot = id >> 3;
    const int combo = slot & 7;               // 8 combos adjacent on one XCD
    const int wdx = (slot >> 3) * 8 + xcd;    // 0..2047

    const int e = combo >> 2;
    const int sflag = combo & 3;
    const int shq = (sflag >> 1) & 1;
    const int swq = sflag & 1;
    const int sh = shq ? 4 : 0, sw = swq ? 4 : 0;
    const __hip_bfloat16* qf = e ? q2 : q0;
    const __hip_bfloat16* kf = e ? k0 : k2;
    float* f1 = e ? f1e1 : f1e0;
    float* f0 = e ? f0e1 : f0e0;

    const int b = wdx >> 10;
    const int s1i = (wdx >> 5) & 31;
    const int s2i = wdx & 31;

    __shared__ __align__(16) char wsm[32768];   // qt 16KB | kt 16KB (linear 256B rows)
    __hip_bfloat16* qt = (__hip_bfloat16*)wsm;
    __hip_bfloat16* kt = (__hip_bfloat16*)(wsm + 16384);
    float* cls = (float*)wsm;                 // aliases qt/kt after MFMA phase
    __shared__ float cmid[81], fxm[81], fym[81];
    __shared__ float sb[225];

    const int tid = threadIdx.x;
    if (tid < 225) sb[tid] = btab[tid];

    // ---- DMA staging: linear LDS dest, XOR-preswizzled global source ----
    for (int idx = tid; idx < 2048; idx += 256) {
        int which = idx >> 10;
        int p = (idx >> 4) & 63, lc = idx & 15;
        int iy = p >> 3, ix = p & 7;
        int gy = (s1i * 8 + iy + sh) & 255;
        int gx = (s2i * 8 + ix + sw) & 255;
        const __hip_bfloat16* srcf = which ? kf : qf;
        const __hip_bfloat16* g = srcf + ((((size_t)b * HH + gy) * WW + gx) << 7)
                                       + ((lc ^ (p & 7)) << 3);
        __hip_bfloat16* dstt = which ? kt : qt;
        gload_lds16(g, dstt + p * 128 + lc * 8);
    }
    __syncthreads();   // drains DMA (vmcnt 0) + sb

    // corr = qw . kw^T   (M=64, N=64, K=128), 4 waves over M
    const int lane = tid & 63;
    const int wv = tid >> 6;
    const int l15 = lane & 15;
    const int kq = lane >> 4;

    f32x4 acc[4];
#pragma unroll
    for (int nf = 0; nf < 4; nf++) acc[nf] = (f32x4){0.f, 0.f, 0.f, 0.f};

#pragma unroll
    for (int kc = 0; kc < 4; ++kc) {
        const int swz = ((kc * 4 + kq) ^ (l15 & 7)) << 4;   // row&7 == l15&7 for A and B
        bf16x8 a = *(const bf16x8*)((const char*)qt + (wv * 16 + l15) * 256 + swz);
#pragma unroll
        for (int nf = 0; nf < 4; ++nf) {
            bf16x8 bb = *(const bf16x8*)((const char*)kt + (nf * 16 + l15) * 256 + swz);
            acc[nf] = __builtin_amdgcn_mfma_f32_16x16x32_bf16(a, bb, acc[nf], 0, 0, 0);
        }
    }
    __syncthreads();   // qt/kt reads complete before cls overwrites them

    // epilogue: scale + relative-pos bias (+ shift mask only on boundary windows)
    const bool needm = (shq && s1i == 31) || (swq && s2i == 31);
#pragma unroll
    for (int nf = 0; nf < 4; ++nf) {
#pragma unroll
        for (int r = 0; r < 4; ++r) {
            int row = wv * 16 + kq * 4 + r;
            int col = nf * 16 + l15;
            int qy = row >> 3, qx = row & 7;
            int ty = col >> 3, tx = col & 7;
            float v = acc[nf][r] * SCALEF + sb[(qy - ty + 7) * 15 + (qx - tx + 7)];
            if (needm) {
                int rhq = 0, rwq = 0, rht = 0, rwt = 0;
                if (shq && s1i == 31) { rhq = (qy < 4) ? 1 : 2; rht = (ty < 4) ? 1 : 2; }
                if (swq && s2i == 31) { rwq = (qx < 4) ? 1 : 2; rwt = (tx < 4) ? 1 : 2; }
                int regq, regt;
                if (shq && swq) { regq = rhq * 3 + rwq; regt = rht * 3 + rwt; }
                else if (shq)   { regq = rhq; regt = rht; }
                else            { regq = rwq; regt = rwt; }
                if (regq != regt) v -= 40.0f;
            }
            cls[row * CST + col] = v;
        }
    }
    __syncthreads();

    const int rg = tid >> 4;       // 16 row-groups
    const int lg = tid & 15;       // 16 lanes per row

    // ---- flow_bsd: 16 rows, 16-lane groups, no-max softmax ----
    {
        int fy = rg >> 2, fx = rg & 3;
        int qy = fy + 2, qx = fx + 2;
        const float* rowp = &cls[(qy * 8 + qx) * CST];
        float S = 0.f, sx = 0.f, sy = 0.f;
#pragma unroll
        for (int j = 0; j < 4; ++j) {
            int t = lg * 4 + j;
            float p = __expf(rowp[t]);
            S += p; sx += p * (float)(t & 7); sy += p * (float)(t >> 3);
        }
#pragma unroll
        for (int m = 8; m >= 1; m >>= 1) {
            S += __shfl_xor(S, m); sx += __shfl_xor(sx, m); sy += __shfl_xor(sy, m);
        }
        if (lg == 0) {
            float fxv = sx / S - (float)qx;
            float fyv = sy / S - (float)qy;
            int Y = (s1i * 8 + shq * 4 + fy + 2) & 255;
            int X = (s2i * 8 + swq * 4 + fx + 2) & 255;
            size_t base = (size_t)b * 2 * HH * WW;
            f0[base + (size_t)Y * WW + X] = fxv;
            f0[base + (size_t)HH * WW + (size_t)Y * WW + X] = fyv;
        }
    }

    // ---- flow_mid row softmaxes: 81 rows, 16 at a time, no-max ----
    // loop-invariant per-lane offsets: addr = base(a,bc) + off[j]
    int offj[4], h2j[4], w2j[4];
#pragma unroll
    for (int j = 0; j < 4; ++j) {
        int t = lg + 16 * j;
        h2j[j] = t >> 3; w2j[j] = t & 7;
        offj[j] = t - h2j[j] * (8 * CST) - w2j[j] * CST;
    }
    for (int it = 0; it < 6; ++it) {
        int rm = it * 16 + rg;
        if (rm < 81) {
            int a = rm / 9, bc = rm - a * 9;
            int ay = a + 3, bx = bc + 3;
            int base = (ay * 8 + bx) * CST;
            float S = 0.f, sc = 0.f, sx = 0.f, sy = 0.f;
#pragma unroll
            for (int j = 0; j < 4; ++j) {
                float v = 0.0f;
                if ((unsigned)(ay - h2j[j]) < 8u && (unsigned)(bx - w2j[j]) < 8u)
                    v = cls[base + offj[j]];
                float p = __expf(v);
                S += p; sc += v * p;
                sx += p * (float)w2j[j]; sy += p * (float)h2j[j];
            }
#pragma unroll
            for (int m = 8; m >= 1; m >>= 1) {
                S += __shfl_xor(S, m); sc += __shfl_xor(sc, m);
                sx += __shfl_xor(sx, m); sy += __shfl_xor(sy, m);
            }
            if (lg == 0) {
                float inv = 1.0f / S;
                cmid[rm] = sc * inv;
                fxm[rm] = sx * inv - (float)bx * 0.5f;
                fym[rm] = sy * inv - (float)ay * 0.5f;
            }
        }
    }
    __syncthreads();

    // flow_mid quadrant combine -> 8x8 (no-max softmax over 4; cmid >= ~-45
    // so exp stays normal fp32)
    if (tid < 64) {
        int fy = tid >> 3, fx = tid & 7;
        int i00 = fy * 9 + fx, i01 = i00 + 1, i10 = i00 + 9, i11 = i00 + 10;
        float p0 = __expf(cmid[i00]), p1 = __expf(cmid[i01]);
        float p2 = __expf(cmid[i10]), p3 = __expf(cmid[i11]);
        float S = p0 + p1 + p2 + p3;
        float ox = 2.0f * (p0 * fxm[i00] + p1 * fxm[i01] + p2 * fxm[i10] + p3 * fxm[i11]) / S;
        float oy = 2.0f * (p0 * fym[i00] + p1 * fym[i01] + p2 * fym[i10] + p3 * fym[i11]) / S;
        int Y = (s1i * 16 + shq * 8 + fy + 4) & 511;
        int X = (s2i * 16 + swq * 8 + fx + 4) & 511;
        size_t base = (size_t)b * 2 * 512 * 512;
        f1[base + (size_t)Y * 512 + X] = ox;
        f1[base + (size_t)512 * 512 + (size_t)Y * 512 + X] = oy;
    }
}

// ---------------------------------------------------------------------------
// K5: bilinear resize (half-pixel, edge clamp) + scale, concat 4 outputs
// ---------------------------------------------------------------------------
__global__ __launch_bounds__(256) void resize_out(
    const float* __restrict__ f1e0, const float* __restrict__ f1e1,
    const float* __restrict__ f0e0, const float* __restrict__ f0e1,
    float* __restrict__ out)
{
    int idx = blockIdx.x * 256 + threadIdx.x;       // 0 .. 16777215
    int o = idx >> 22;
    int rem = idx & 4194303;
    int bc = rem >> 20;                              // b*2+ch
    int Y = (rem >> 10) & 1023;
    int X = rem & 1023;
    const float* src; int n; float invf, sc;
    if (o == 0)      { src = f1e1; n = 512; invf = 0.5f;  sc = 2.f; }
    else if (o == 1) { src = f1e0; n = 512; invf = 0.5f;  sc = 2.f; }
    else if (o == 2) { src = f0e0; n = 256; invf = 0.25f; sc = 4.f; }
    else             { src = f0e1; n = 256; invf = 0.25f; sc = 4.f; }
    float syf = ((float)Y + 0.5f) * invf - 0.5f;
    float sxf = ((float)X + 0.5f) * invf - 0.5f;
    int iy = (int)floorf(syf), ix = (int)floorf(sxf);
    float wy = syf - (float)iy, wx = sxf - (float)ix;
    int y0c = min(max(iy, 0), n - 1), y1c = min(max(iy + 1, 0), n - 1);
    int x0c = min(max(ix, 0), n - 1), x1c = min(max(ix + 1, 0), n - 1);
    const float* s = src + (size_t)bc * n * n;
    float v00 = s[(size_t)y0c * n + x0c], v01 = s[(size_t)y0c * n + x1c];
    float v10 = s[(size_t)y1c * n + x0c], v11 = s[(size_t)y1c * n + x1c];
    float v = (1.f - wy) * ((1.f - wx) * v00 + wx * v01) + wy * ((1.f - wx) * v10 + wx * v11);
    out[idx] = v * sc;
}

// ---------------------------------------------------------------------------
extern "C" void kernel_launch(void* const* d_in, const int* in_sizes, int n_in,
                              void* d_out, int out_size, void* d_ws, size_t ws_size,
                              hipStream_t stream)
{
    const float* feat0 = (const float*)d_in[0];
    const float* feat2 = (const float*)d_in[1];
    const float* wq = (const float*)d_in[2];
    const float* bq = (const float*)d_in[3];
    const float* wk = (const float*)d_in[4];
    const float* bk = (const float*)d_in[5];
    const float* btab = (const float*)d_in[6];

    char* w = (char*)d_ws;
    const size_t F = (size_t)16777216 * 2;   // bytes per bf16 NHWC field (2*256*256*128)
    __hip_bfloat16* q0 = (__hip_bfloat16*)(w);
    __hip_bfloat16* k0 = (__hip_bfloat16*)(w + F);
    __hip_bfloat16* q2 = (__hip_bfloat16*)(w + 2 * F);
    __hip_bfloat16* k2 = (__hip_bfloat16*)(w + 3 * F);
    __hip_bfloat16* in0T = (__hip_bfloat16*)(w + 4 * F);
    __hip_bfloat16* in1T = (__hip_bfloat16*)(w + 5 * F);
    __hip_bfloat16* w3q = (__hip_bfloat16*)(w + 6 * F);
    __hip_bfloat16* w3k = (__hip_bfloat16*)(w + 6 * F + 294912);
    float* f1e0 = (float*)(w + 6 * F + 2 * 294912);
    float* f1e1 = f1e0 + 1048576;   // 2*2*512*512
    float* f0e0 = f1e1 + 1048576;
    float* f0e1 = f0e0 + 262144;    // 2*2*256*256

    hipLaunchKernelGGL(transpose_nhwc, dim3(16384), dim3(256), 0, stream, feat0, in0T);
    hipLaunchKernelGGL(transpose_nhwc, dim3(16384), dim3(256), 0, stream, feat2, in1T);
    hipLaunchKernelGGL(prep_w, dim3(576), dim3(256), 0, stream, wq, wk, w3q, w3k);
    hipLaunchKernelGGL(conv3x3_mfma, dim3(2048, 2), dim3(256), 0, stream,
                       in0T, in1T, w3q, w3k, bq, bk, q0, k0, q2, k2);
    hipLaunchKernelGGL(window_flow, dim3(16384), dim3(256), 0, stream,
                       q0, k0, q2, k2, btab, f1e0, f1e1, f0e0, f0e1);
    hipLaunchKernelGGL(resize_out, dim3(65536), dim3(256), 0, stream,
                       f1e0, f1e1, f0e0, f0e1, (float*)d_out);
}

// Round 10
// 368.634 us; speedup vs baseline: 2.1561x; 1.0200x over previous
//
#include <hip/hip_runtime.h>
#include <hip/hip_bf16.h>
#include <math.h>

typedef __attribute__((ext_vector_type(8))) __bf16 bf16x8;
typedef __attribute__((ext_vector_type(4))) float f32x4;
typedef __attribute__((ext_vector_type(16))) float f32x16;

#define HH 256
#define WW 256
#define SCALEF 0.08838834764831845f  // 128^-0.5

__device__ __forceinline__ void gload_lds16(const void* g, void* l) {
    __builtin_amdgcn_global_load_lds(
        (const __attribute__((address_space(1))) void*)g,
        (__attribute__((address_space(3))) void*)l, 16, 0, 0);
}

// ---------------------------------------------------------------------------
// K1: NCHW f32 -> NHWC bf16 transpose
// ---------------------------------------------------------------------------
__global__ __launch_bounds__(256) void transpose_nhwc(const float* __restrict__ in,
                                                      __hip_bfloat16* __restrict__ out)
{
    int blk = blockIdx.x;
    int c0 = (blk & 3) * 32;
    int x0 = ((blk >> 2) & 7) * 32;
    int by = blk >> 5;              // b*256 + y
    int y = by & 255, b = by >> 8;
    __shared__ float tile[32][33];
    int tx = threadIdx.x & 31, ty = threadIdx.x >> 5;   // ty 0..7
#pragma unroll
    for (int i = 0; i < 4; i++) {
        int c = c0 + ty + 8 * i;
        tile[ty + 8 * i][tx] = in[(((size_t)b * 128 + c) * HH + y) * WW + x0 + tx];
    }
    __syncthreads();
#pragma unroll
    for (int i = 0; i < 4; i++) {
        int x = x0 + ty + 8 * i;
        out[(((size_t)b * HH + y) * WW + x) * 128 + c0 + tx] =
            __float2bfloat16(tile[tx][ty + 8 * i]);
    }
}

// ---------------------------------------------------------------------------
// K2: weight repack -> K16-chunk-major, lane-contiguous for 32x32x16 B frags.
// kg = tap*128+ci; chunk qc = kg>>4 (72 chunks of 2048 elem).
// dst = qc*2048 + (co>>5)*512 + ((kg>>3)&1)*256 + (co&31)*8 + (kg&7)
// Read (wave c-half, frag n, lane l): off = (c*2+n)*512 + l*8  -> contiguous.
// ---------------------------------------------------------------------------
__global__ __launch_bounds__(256) void prep_w(const float* __restrict__ wq,
                                              const float* __restrict__ wk,
                                              __hip_bfloat16* __restrict__ w3q,
                                              __hip_bfloat16* __restrict__ w3k)
{
    int i = blockIdx.x * 256 + threadIdx.x;
    if (i >= 128 * 128 * 9) return;
    int co = i / (128 * 9);
    int r = i - co * 128 * 9;
    int ci = r / 9;
    int tap = r - ci * 9;
    int kg = tap * 128 + ci;
    int qc = kg >> 4;
    int kin = kg & 15;
    int dst = qc * 2048 + (co >> 5) * 512 + (kin >> 3) * 256 + (co & 31) * 8 + (kin & 7);
    w3q[dst] = __float2bfloat16(wq[i]);
    w3k[dst] = __float2bfloat16(wk[i]);
}

// ---------------------------------------------------------------------------
// K3: conv3x3 (SAME) implicit GEMM, q+k merged, 32x32x16 MFMA.
// Block: 16x8 px tile (M=128), 128 co, both mats. 4 waves:
//   wave (p = wv>>1, c = wv&1): px rows [4p,4p+4) x co [64c,64c+64) x {q,k}.
// Per K16 chunk/wave: 2 A frags + 4 B frags (6KB LDS) -> 8 MFMAs (42.7 FLOP/B).
// A: halo patch [10][18]x128ch, 256B rows, slot-XOR swizzle.
// B: 72 chunks (9 taps x 8 K16), 8KB each (q+k), triple-buffered DMA, dist 2,
//    counted vmcnt(2); lane-contiguous frag reads (conflict-free).
// Out: 32x32 C/D map col=lane&31, row=(reg&3)+8*(reg>>2)+4*(lane>>5);
//      staged bf16 in LDS (aliases patch) -> coalesced uint4 stores.
// ---------------------------------------------------------------------------
__global__ __launch_bounds__(256, 2) void conv3x3_mfma(
    const __hip_bfloat16* __restrict__ in0, const __hip_bfloat16* __restrict__ in1,
    const __hip_bfloat16* __restrict__ w3q, const __hip_bfloat16* __restrict__ w3k,
    const float* __restrict__ bq, const float* __restrict__ bk,
    __hip_bfloat16* __restrict__ q0, __hip_bfloat16* __restrict__ k0,
    __hip_bfloat16* __restrict__ q2, __hip_bfloat16* __restrict__ k2)
{
    const int half = blockIdx.y;          // 0: in0 -> (q0,k0), 1: in1 -> (q2,k2)
    const __hip_bfloat16* src = half ? in1 : in0;
    __hip_bfloat16* qdst = half ? q2 : q0;
    __hip_bfloat16* kdst = half ? k2 : k0;

    const int blk = blockIdx.x;           // 0..1023
    const int b = blk >> 9;
    const int rr = blk & 511;
    const int y0 = (rr >> 4) << 3;        // 32 tile-rows of 8
    const int x0 = (rr & 15) << 4;        // 16 tile-cols of 16

    __shared__ __align__(16) char smem[46080 + 24576];  // patch 180*256B + B 3x8KB
    char* patch = smem;
    char* ldsB = smem + 46080;

    const int tid = threadIdx.x;

    // ---- stage input halo patch (10x18 pos, 16 slots each, slot-XOR swizzle)
    for (int idx = tid; idx < 2880; idx += 256) {
        int p = idx >> 4, lc = idx & 15;
        int py = p / 18, px_ = p - py * 18;
        int gy = y0 + py - 1, gx = x0 + px_ - 1;
        uint4 v = make_uint4(0u, 0u, 0u, 0u);
        if (gy >= 0 && gy < HH && gx >= 0 && gx < WW)
            v = *(const uint4*)(src + ((((size_t)b * HH + gy) * WW + gx) << 7) + lc * 8);
        *(uint4*)(patch + p * 256 + (((lc & 8) | ((lc ^ p) & 7)) << 4)) = v;
    }
    // ---- async-stage chunks 0,1 of both mats ----
    {
        const char* sq = (const char*)w3q + tid * 16;
        const char* sk = (const char*)w3k + tid * 16;
#pragma unroll
        for (int cb = 0; cb < 2; ++cb) {
            char* dl = ldsB + cb * 8192 + tid * 16;
            gload_lds16(sq + cb * 4096, dl);
            gload_lds16(sk + cb * 4096, dl + 4096);
        }
    }
    __syncthreads();   // full drain (patch + chunks 0,1)

    const int lane = tid & 63;
    const int wv = tid >> 6;
    const int p = wv >> 1, c = wv & 1;
    const int l31 = lane & 31;
    const int ks = lane >> 5;             // k-half within K16
    const int rowl = (lane >> 4) & 1;     // row within frag's 2 tile-rows
    const int coll = lane & 15;           // tile col
    const int ybase = p * 4;
    const int cN0 = c * 2048 + lane * 16; // B frag n=0 byte offset
    const int cN1 = cN0 + 1024;          // n=1

    f32x16 accq[2][2], acck[2][2];
#pragma unroll
    for (int m = 0; m < 2; ++m)
#pragma unroll
        for (int n = 0; n < 2; ++n) {
            accq[m][n] = (f32x16)(0.f);
            acck[m][n] = (f32x16)(0.f);
        }

#pragma unroll
    for (int q = 0; q < 72; ++q) {
        const int tap = q >> 3, cc8 = q & 7;
        const int ky = tap / 3, kx = tap - ky * 3;
        if (q + 2 < 72) {                 // prefetch distance 2 -> buf[(q+2)%3]
            const char* sq = (const char*)w3q + (size_t)(q + 2) * 4096 + tid * 16;
            const char* sk = (const char*)w3k + (size_t)(q + 2) * 4096 + tid * 16;
            char* dl = ldsB + ((q + 2) % 3) * 8192 + tid * 16;
            gload_lds16(sq, dl);
            gload_lds16(sk, dl + 4096);
        }
        const char* bb = ldsB + (q % 3) * 8192;
        bf16x8 fq0 = *(const bf16x8*)(bb + cN0);
        bf16x8 fq1 = *(const bf16x8*)(bb + cN1);
        bf16x8 fk0 = *(const bf16x8*)(bb + 4096 + cN0);
        bf16x8 fk1 = *(const bf16x8*)(bb + 4096 + cN1);
        const int s = cc8 * 2 + ks;       // 16B slot within 256B channel row
#pragma unroll
        for (int m = 0; m < 2; ++m) {
            int pos = (ybase + m * 2 + rowl + ky) * 18 + coll + kx;
            bf16x8 a = *(const bf16x8*)(patch + pos * 256 +
                                        (((s & 8) | ((s ^ pos) & 7)) << 4));
            accq[m][0] = __builtin_amdgcn_mfma_f32_32x32x16_bf16(a, fq0, accq[m][0], 0, 0, 0);
            accq[m][1] = __builtin_amdgcn_mfma_f32_32x32x16_bf16(a, fq1, accq[m][1], 0, 0, 0);
            acck[m][0] = __builtin_amdgcn_mfma_f32_32x32x16_bf16(a, fk0, acck[m][0], 0, 0, 0);
            acck[m][1] = __builtin_amdgcn_mfma_f32_32x32x16_bf16(a, fk1, acck[m][1], 0, 0, 0);
        }
        if (q + 1 < 72) {
            if (q + 2 < 72) asm volatile("s_waitcnt vmcnt(2)" ::: "memory");
            else            asm volatile("s_waitcnt vmcnt(0)" ::: "memory");
            __builtin_amdgcn_s_barrier();
            __builtin_amdgcn_sched_barrier(0);
        }
    }
    __syncthreads();   // all patch/B reads done before stage overwrite

    // ---- epilogue: 32x32 C/D map, stage bf16 [128 px][stride 136] over patch
    float bvq[2] = { bq[c * 64 + l31], bq[c * 64 + 32 + l31] };
    float bvk[2] = { bk[c * 64 + l31], bk[c * 64 + 32 + l31] };
    __hip_bfloat16* stage = (__hip_bfloat16*)patch;

#pragma unroll
    for (int m = 0; m < 2; ++m)
#pragma unroll
        for (int n = 0; n < 2; ++n)
#pragma unroll
            for (int reg = 0; reg < 16; ++reg) {
                int px = p * 64 + m * 32 + (reg & 3) + 8 * (reg >> 2) + 4 * ks;
                stage[px * 136 + c * 64 + n * 32 + l31] =
                    __float2bfloat16(accq[m][n][reg] + bvq[n]);
            }
    __syncthreads();
#pragma unroll
    for (int it = 0; it < 8; ++it) {
        int idx = it * 256 + tid;
        int px = idx >> 4, lc = idx & 15;
        int y = y0 + (px >> 4), x = x0 + (px & 15);
        uint4 v = *(const uint4*)((const char*)patch + px * 272 + lc * 16);
        *(uint4*)(qdst + ((((size_t)b * HH + y) * WW + x) << 7) + lc * 8) = v;
    }
    __syncthreads();   // q-stage reads done before k-stage overwrite
#pragma unroll
    for (int m = 0; m < 2; ++m)
#pragma unroll
        for (int n = 0; n < 2; ++n)
#pragma unroll
            for (int reg = 0; reg < 16; ++reg) {
                int px = p * 64 + m * 32 + (reg & 3) + 8 * (reg >> 2) + 4 * ks;
                stage[px * 136 + c * 64 + n * 32 + l31] =
                    __float2bfloat16(acck[m][n][reg] + bvk[n]);
            }
    __syncthreads();
#pragma unroll
    for (int it = 0; it < 8; ++it) {
        int idx = it * 256 + tid;
        int px = idx >> 4, lc = idx & 15;
        int y = y0 + (px >> 4), x = x0 + (px & 15);
        uint4 v = *(const uint4*)((const char*)patch + px * 272 + lc * 16);
        *(uint4*)(kdst + ((((size_t)b * HH + y) * WW + x) << 7) + lc * 8) = v;
    }
}

// ---------------------------------------------------------------------------
// K4: per-(window, estimate x shift) correlation + flow_bsd + flow_mid.
// qt/kt: linear 256B rows staged via global_load_lds with XOR-preswizzled
// source; reads apply the same XOR (both-sides involution).
// Softmax: NO max-subtract; mask constant -40 (shift-invariance keeps
// fully-masked rows exact, no underflow/NaN).
// ---------------------------------------------------------------------------
#define CST 66       // cls row stride (floats)
__global__ __launch_bounds__(256, 4) void window_flow(
    const __hip_bfloat16* __restrict__ q0, const __hip_bfloat16* __restrict__ k0,
    const __hip_bfloat16* __restrict__ q2, const __hip_bfloat16* __restrict__ k2,
    const float* __restrict__ btab,
    float* __restrict__ f1e0, float* __restrict__ f1e1,
    float* __restrict__ f0e0, float* __restrict__ f0e1)
{
    const int id = blockIdx.x;               // 0..16383
    const int xcd = id & 7;
    const int slot = id >> 3;
    const int combo = slot & 7;               // 8 combos adjacent on one XCD
    const int wdx = (slot >> 3) * 8 + xcd;    // 0..2047

    const int e = combo >> 2;
    const int sflag = combo & 3;
    const int shq = (sflag >> 1) & 1;
    const int swq = sflag & 1;
    const int sh = shq ? 4 : 0, sw = swq ? 4 : 0;
    const __hip_bfloat16* qf = e ? q2 : q0;
    const __hip_bfloat16* kf = e ? k0 : k2;
    float* f1 = e ? f1e1 : f1e0;
    float* f0 = e ? f0e1 : f0e0;

    const int b = wdx >> 10;
    const int s1i = (wdx >> 5) & 31;
    const int s2i = wdx & 31;

    __shared__ __align__(16) char wsm[32768];   // qt 16KB | kt 16KB (linear 256B rows)
    __hip_bfloat16* qt = (__hip_bfloat16*)wsm;
    __hip_bfloat16* kt = (__hip_bfloat16*)(wsm + 16384);
    float* cls = (float*)wsm;                 // aliases qt/kt after MFMA phase
    __shared__ float cmid[81], fxm[81], fym[81];
    __shared__ float sb[225];

    const int tid = threadIdx.x;
    if (tid < 225) sb[tid] = btab[tid];

    // ---- DMA staging: linear LDS dest, XOR-preswizzled global source ----
    for (int idx = tid; idx < 2048; idx += 256) {
        int which = idx >> 10;
        int p = (idx >> 4) & 63, lc = idx & 15;
        int iy = p >> 3, ix = p & 7;
        int gy = (s1i * 8 + iy + sh) & 255;
        int gx = (s2i * 8 + ix + sw) & 255;
        const __hip_bfloat16* srcf = which ? kf : qf;
        const __hip_bfloat16* g = srcf + ((((size_t)b * HH + gy) * WW + gx) << 7)
                                       + ((lc ^ (p & 7)) << 3);
        __hip_bfloat16* dstt = which ? kt : qt;
        gload_lds16(g, dstt + p * 128 + lc * 8);
    }
    __syncthreads();   // drains DMA (vmcnt 0) + sb

    // corr = qw . kw^T   (M=64, N=64, K=128), 4 waves over M
    const int lane = tid & 63;
    const int wv = tid >> 6;
    const int l15 = lane & 15;
    const int kq = lane >> 4;

    f32x4 acc[4];
#pragma unroll
    for (int nf = 0; nf < 4; nf++) acc[nf] = (f32x4){0.f, 0.f, 0.f, 0.f};

#pragma unroll
    for (int kc = 0; kc < 4; ++kc) {
        const int swz = ((kc * 4 + kq) ^ (l15 & 7)) << 4;   // row&7 == l15&7 for A and B
        bf16x8 a = *(const bf16x8*)((const char*)qt + (wv * 16 + l15) * 256 + swz);
#pragma unroll
        for (int nf = 0; nf < 4; ++nf) {
            bf16x8 bb = *(const bf16x8*)((const char*)kt + (nf * 16 + l15) * 256 + swz);
            acc[nf] = __builtin_amdgcn_mfma_f32_16x16x32_bf16(a, bb, acc[nf], 0, 0, 0);
        }
    }
    __syncthreads();   // qt/kt reads complete before cls overwrites them

    // epilogue: scale + relative-pos bias (+ shift mask only on boundary windows)
    const bool needm = (shq && s1i == 31) || (swq && s2i == 31);
#pragma unroll
    for (int nf = 0; nf < 4; ++nf) {
#pragma unroll
        for (int r = 0; r < 4; ++r) {
            int row = wv * 16 + kq * 4 + r;
            int col = nf * 16 + l15;
            int qy = row >> 3, qx = row & 7;
            int ty = col >> 3, tx = col & 7;
            float v = acc[nf][r] * SCALEF + sb[(qy - ty + 7) * 15 + (qx - tx + 7)];
            if (needm) {
                int rhq = 0, rwq = 0, rht = 0, rwt = 0;
                if (shq && s1i == 31) { rhq = (qy < 4) ? 1 : 2; rht = (ty < 4) ? 1 : 2; }
                if (swq && s2i == 31) { rwq = (qx < 4) ? 1 : 2; rwt = (tx < 4) ? 1 : 2; }
                int regq, regt;
                if (shq && swq) { regq = rhq * 3 + rwq; regt = rht * 3 + rwt; }
                else if (shq)   { regq = rhq; regt = rht; }
                else            { regq = rwq; regt = rwt; }
                if (regq != regt) v -= 40.0f;
            }
            cls[row * CST + col] = v;
        }
    }
    __syncthreads();

    const int rg = tid >> 4;       // 16 row-groups
    const int lg = tid & 15;       // 16 lanes per row

    // ---- flow_bsd: 16 rows, 16-lane groups, no-max softmax ----
    {
        int fy = rg >> 2, fx = rg & 3;
        int qy = fy + 2, qx = fx + 2;
        const float* rowp = &cls[(qy * 8 + qx) * CST];
        float S = 0.f, sx = 0.f, sy = 0.f;
#pragma unroll
        for (int j = 0; j < 4; ++j) {
            int t = lg * 4 + j;
            float p = __expf(rowp[t]);
            S += p; sx += p * (float)(t & 7); sy += p * (float)(t >> 3);
        }
#pragma unroll
        for (int m = 8; m >= 1; m >>= 1) {
            S += __shfl_xor(S, m); sx += __shfl_xor(sx, m); sy += __shfl_xor(sy, m);
        }
        if (lg == 0) {
            float fxv = sx / S - (float)qx;
            float fyv = sy / S - (float)qy;
            int Y = (s1i * 8 + shq * 4 + fy + 2) & 255;
            int X = (s2i * 8 + swq * 4 + fx + 2) & 255;
            size_t base = (size_t)b * 2 * HH * WW;
            f0[base + (size_t)Y * WW + X] = fxv;
            f0[base + (size_t)HH * WW + (size_t)Y * WW + X] = fyv;
        }
    }

    // ---- flow_mid row softmaxes: 81 rows, 16 at a time, no-max ----
    int offj[4], h2j[4], w2j[4];
#pragma unroll
    for (int j = 0; j < 4; ++j) {
        int t = lg + 16 * j;
        h2j[j] = t >> 3; w2j[j] = t & 7;
        offj[j] = t - h2j[j] * (8 * CST) - w2j[j] * CST;
    }
    for (int it = 0; it < 6; ++it) {
        int rm = it * 16 + rg;
        if (rm < 81) {
            int a = rm / 9, bc = rm - a * 9;
            int ay = a + 3, bx = bc + 3;
            int base = (ay * 8 + bx) * CST;
            float S = 0.f, sc = 0.f, sx = 0.f, sy = 0.f;
#pragma unroll
            for (int j = 0; j < 4; ++j) {
                float v = 0.0f;
                if ((unsigned)(ay - h2j[j]) < 8u && (unsigned)(bx - w2j[j]) < 8u)
                    v = cls[base + offj[j]];
                float p = __expf(v);
                S += p; sc += v * p;
                sx += p * (float)w2j[j]; sy += p * (float)h2j[j];
            }
#pragma unroll
            for (int m = 8; m >= 1; m >>= 1) {
                S += __shfl_xor(S, m); sc += __shfl_xor(sc, m);
                sx += __shfl_xor(sx, m); sy += __shfl_xor(sy, m);
            }
            if (lg == 0) {
                float inv = 1.0f / S;
                cmid[rm] = sc * inv;
                fxm[rm] = sx * inv - (float)bx * 0.5f;
                fym[rm] = sy * inv - (float)ay * 0.5f;
            }
        }
    }
    __syncthreads();

    // flow_mid quadrant combine -> 8x8 (no-max softmax over 4)
    if (tid < 64) {
        int fy = tid >> 3, fx = tid & 7;
        int i00 = fy * 9 + fx, i01 = i00 + 1, i10 = i00 + 9, i11 = i00 + 10;
        float p0 = __expf(cmid[i00]), p1 = __expf(cmid[i01]);
        float p2 = __expf(cmid[i10]), p3 = __expf(cmid[i11]);
        float S = p0 + p1 + p2 + p3;
        float ox = 2.0f * (p0 * fxm[i00] + p1 * fxm[i01] + p2 * fxm[i10] + p3 * fxm[i11]) / S;
        float oy = 2.0f * (p0 * fym[i00] + p1 * fym[i01] + p2 * fym[i10] + p3 * fym[i11]) / S;
        int Y = (s1i * 16 + shq * 8 + fy + 4) & 511;
        int X = (s2i * 16 + swq * 8 + fx + 4) & 511;
        size_t base = (size_t)b * 2 * 512 * 512;
        f1[base + (size_t)Y * 512 + X] = ox;
        f1[base + (size_t)512 * 512 + (size_t)Y * 512 + X] = oy;
    }
}

// ---------------------------------------------------------------------------
// K5: bilinear resize (half-pixel, edge clamp) + scale, concat 4 outputs
// ---------------------------------------------------------------------------
__global__ __launch_bounds__(256) void resize_out(
    const float* __restrict__ f1e0, const float* __restrict__ f1e1,
    const float* __restrict__ f0e0, const float* __restrict__ f0e1,
    float* __restrict__ out)
{
    int idx = blockIdx.x * 256 + threadIdx.x;       // 0 .. 16777215
    int o = idx >> 22;
    int rem = idx & 4194303;
    int bc = rem >> 20;                              // b*2+ch
    int Y = (rem >> 10) & 1023;
    int X = rem & 1023;
    const float* src; int n; float invf, sc;
    if (o == 0)      { src = f1e1; n = 512; invf = 0.5f;  sc = 2.f; }
    else if (o == 1) { src = f1e0; n = 512; invf = 0.5f;  sc = 2.f; }
    else if (o == 2) { src = f0e0; n = 256; invf = 0.25f; sc = 4.f; }
    else             { src = f0e1; n = 256; invf = 0.25f; sc = 4.f; }
    float syf = ((float)Y + 0.5f) * invf - 0.5f;
    float sxf = ((float)X + 0.5f) * invf - 0.5f;
    int iy = (int)floorf(syf), ix = (int)floorf(sxf);
    float wy = syf - (float)iy, wx = sxf - (float)ix;
    int y0c = min(max(iy, 0), n - 1), y1c = min(max(iy + 1, 0), n - 1);
    int x0c = min(max(ix, 0), n - 1), x1c = min(max(ix + 1, 0), n - 1);
    const float* s = src + (size_t)bc * n * n;
    float v00 = s[(size_t)y0c * n + x0c], v01 = s[(size_t)y0c * n + x1c];
    float v10 = s[(size_t)y1c * n + x0c], v11 = s[(size_t)y1c * n + x1c];
    float v = (1.f - wy) * ((1.f - wx) * v00 + wx * v01) + wy * ((1.f - wx) * v10 + wx * v11);
    out[idx] = v * sc;
}

// ---------------------------------------------------------------------------
extern "C" void kernel_launch(void* const* d_in, const int* in_sizes, int n_in,
                              void* d_out, int out_size, void* d_ws, size_t ws_size,
                              hipStream_t stream)
{
    const float* feat0 = (const float*)d_in[0];
    const float* feat2 = (const float*)d_in[1];
    const float* wq = (const float*)d_in[2];
    const float* bq = (const float*)d_in[3];
    const float* wk = (const float*)d_in[4];
    const float* bk = (const float*)d_in[5];
    const float* btab = (const float*)d_in[6];

    char* w = (char*)d_ws;
    const size_t F = (size_t)16777216 * 2;   // bytes per bf16 NHWC field (2*256*256*128)
    __hip_bfloat16* q0 = (__hip_bfloat16*)(w);
    __hip_bfloat16* k0 = (__hip_bfloat16*)(w + F);
    __hip_bfloat16* q2 = (__hip_bfloat16*)(w + 2 * F);
    __hip_bfloat16* k2 = (__hip_bfloat16*)(w + 3 * F);
    __hip_bfloat16* in0T = (__hip_bfloat16*)(w + 4 * F);
    __hip_bfloat16* in1T = (__hip_bfloat16*)(w + 5 * F);
    __hip_bfloat16* w3q = (__hip_bfloat16*)(w + 6 * F);
    __hip_bfloat16* w3k = (__hip_bfloat16*)(w + 6 * F + 294912);
    float* f1e0 = (float*)(w + 6 * F + 2 * 294912);
    float* f1e1 = f1e0 + 1048576;   // 2*2*512*512
    float* f0e0 = f1e1 + 1048576;
    float* f0e1 = f0e0 + 262144;    // 2*2*256*256

    hipLaunchKernelGGL(transpose_nhwc, dim3(16384), dim3(256), 0, stream, feat0, in0T);
    hipLaunchKernelGGL(transpose_nhwc, dim3(16384), dim3(256), 0, stream, feat2, in1T);
    hipLaunchKernelGGL(prep_w, dim3(576), dim3(256), 0, stream, wq, wk, w3q, w3k);
    hipLaunchKernelGGL(conv3x3_mfma, dim3(1024, 2), dim3(256), 0, stream,
                       in0T, in1T, w3q, w3k, bq, bk, q0, k0, q2, k2);
    hipLaunchKernelGGL(window_flow, dim3(16384), dim3(256), 0, stream,
                       q0, k0, q2, k2, btab, f1e0, f1e1, f0e0, f0e1);
    hipLaunchKernelGGL(resize_out, dim3(65536), dim3(256), 0, stream,
                       f1e0, f1e1, f0e0, f0e1, (float*)d_out);
}